// Round 12
// baseline (292.821 us; speedup 1.0000x reference)
//
#include <hip/hip_runtime.h>

#define N_NODES 100000
#define N_EDGES 600000
#define ZROW N_NODES         // sentinel zero-row index (xb/hb have N_NODES+1 rows)
#define SUBP 128             // dst sub-partitions
#define SUB_SZ 782           // nodes per sub-partition (128*782 = 100096 >= 100000)
#define ECHUNK 2048          // edges per bin_kernel block
#define ACH 293              // ceil(600000/2048)
#define BCAP 6144            // per (rel,subpart) bin capacity (mean 4687, +21 sigma)
// LDS tiles: stride 128 ushorts (256B), XOR-swizzled 16B units -> 32768 B total
// per kernel = exactly 5 blocks/CU (163840/32768). SW gives the ushort offset
// of 16B-unit c16 in row `row`.
#define SW(row, c16) ((((c16) ^ ((row) & 7)) << 3))

typedef __attribute__((ext_vector_type(8))) short short8;
typedef __attribute__((ext_vector_type(4))) float f32x4;
typedef __attribute__((ext_vector_type(8))) unsigned short ushort8v;

__device__ __forceinline__ unsigned short f2b(float f) {   // fp32 -> bf16 RNE
    unsigned u = __builtin_bit_cast(unsigned, f);
    return (unsigned short)((u + 0x7fffu + ((u >> 16) & 1u)) >> 16);
}
__device__ __forceinline__ float b2f(unsigned short b) {
    return __builtin_bit_cast(float, (unsigned)b << 16);
}

// ---------------------------------------------------------------------------
// Pass A: 128-way counting sort of edges by dst sub-partition. Edge packed
// into 4B: src (17b) | local-dst (10b, <782). LDS-staged compaction ->
// line-granular global writes into per-(rel,subpart) bins.
__global__ __launch_bounds__(256) void bin_kernel(const int* __restrict__ e0,
                                                  const int* __restrict__ e1,
                                                  const int* __restrict__ e2,
                                                  unsigned* __restrict__ bins,
                                                  int* __restrict__ bincur) {
    int r = blockIdx.y;
    const int* ei = (r == 0) ? e0 : (r == 1 ? e1 : e2);
    int base = blockIdx.x * ECHUNK;
    int nhere = min(ECHUNK, N_EDGES - base);
    __shared__ int lhist[SUBP], lstart[SUBP], lcur[SUBP], gbase[SUBP];
    __shared__ unsigned led[ECHUNK];
    __shared__ unsigned char lbkt[ECHUNK];
    int tid = threadIdx.x;
    for (int i = tid; i < SUBP; i += 256) { lhist[i] = 0; lcur[i] = 0; }
    __syncthreads();

    unsigned pk[8]; int bn[8];
#pragma unroll
    for (int k = 0; k < 8; k++) {
        int i = tid + k * 256;
        bn[k] = -1;
        if (i < nhere) {
            int e = base + i;
            int s = ei[e], d = ei[N_EDGES + e];
            int b = d / SUB_SZ;
            int ld = d - b * SUB_SZ;
            pk[k] = (unsigned)s | ((unsigned)ld << 17);
            bn[k] = b;
            atomicAdd(&lhist[b], 1);
        }
    }
    __syncthreads();
    if (tid == 0) {
        int run = 0;
        for (int b = 0; b < SUBP; b++) { lstart[b] = run; run += lhist[b]; }
    }
    __syncthreads();
#pragma unroll
    for (int k = 0; k < 8; k++) {
        if (bn[k] >= 0) {
            int slot = atomicAdd(&lcur[bn[k]], 1);
            int p = lstart[bn[k]] + slot;
            led[p] = pk[k];
            lbkt[p] = (unsigned char)bn[k];
        }
    }
    if (tid < SUBP) gbase[tid] = atomicAdd(&bincur[r * SUBP + tid], lhist[tid]);
    __syncthreads();
    for (int i = tid; i < nhere; i += 256) {
        int b = lbkt[i];
        int dstidx = gbase[b] + (i - lstart[b]);
        if (dstidx < BCAP)   // safety clamp: drop (never fault) on overflow
            bins[(size_t)(r * SUBP + b) * BCAP + dstidx] = led[i];
    }
}

// ---------------------------------------------------------------------------
// Consolidated CSR build: one block per (rel,subpart). Inline pbase prefix
// (wave 3) + LDS histogram -> in-LDS scan -> cnt/rowstart -> LDS-cursor fill
// -> coalesced adj streaming.
__global__ __launch_bounds__(256) void csr_kernel(const unsigned* __restrict__ bins,
                                                  const int* __restrict__ bincur,
                                                  int* __restrict__ cnt,
                                                  int* __restrict__ rowstart,
                                                  int* __restrict__ adj) {
    int p = blockIdx.x, r = blockIdx.y;
    int n0 = p * SUB_SZ;
    int nodes = min(SUB_SZ, N_NODES - n0);
    __shared__ int hist[SUB_SZ];
    __shared__ int sstage[BCAP];
    __shared__ int wsums[4];
    __shared__ int s_pb;
    int tid = threadIdx.x, lane = tid & 63, wid = tid >> 6;
    for (int i = tid; i < SUB_SZ; i += 256) hist[i] = 0;
    if (wid == 3) {   // inline prefix over this relation's partition totals
        int v0 = (lane < p) ? bincur[r * SUBP + lane] : 0;
        int v1 = (lane + 64 < p) ? bincur[r * SUBP + 64 + lane] : 0;
        int s = v0 + v1;
#pragma unroll
        for (int off = 1; off < 64; off <<= 1) s += __shfl_xor(s, off);
        if (lane == 0) s_pb = s;
    }
    __syncthreads();
    int len = min(bincur[r * SUBP + p], BCAP);
    const unsigned* b = bins + (size_t)(r * SUBP + p) * BCAP;
    for (int i = tid; i < len; i += 256) atomicAdd(&hist[b[i] >> 17], 1);
    __syncthreads();
    int base4 = tid * 4;
    int v[4]; int tsum = 0;
#pragma unroll
    for (int k = 0; k < 4; k++) {
        int i = base4 + k;
        v[k] = (i < SUB_SZ) ? hist[i] : 0;
        tsum += v[k];
    }
    for (int i = tid; i < nodes; i += 256) cnt[r * N_NODES + n0 + i] = hist[i];
    int incl = tsum;
#pragma unroll
    for (int off = 1; off < 64; off <<= 1) {
        int t = __shfl_up(incl, off);
        if (lane >= off) incl += t;
    }
    if (lane == 63) wsums[wid] = incl;
    __syncthreads();
    if (tid == 0) { int run = 0; for (int w = 0; w < 4; w++) { int t = wsums[w]; wsums[w] = run; run += t; } }
    __syncthreads();
    int excl = incl - tsum + wsums[wid];
    int pb = s_pb;
    int run = excl;
#pragma unroll
    for (int k = 0; k < 4; k++) {
        int i = base4 + k;
        if (i < SUB_SZ) {
            if (i < nodes) rowstart[r * N_NODES + n0 + i] = pb + run;
            hist[i] = run;              // local cursor seed
        }
        run += v[k];
    }
    __syncthreads();
    for (int i = tid; i < len; i += 256) {
        unsigned vv = b[i];
        int pos = atomicAdd(&hist[vv >> 17], 1);
        if (pos < BCAP) sstage[pos] = (int)(vv & 0x1FFFFu);
    }
    __syncthreads();
    int* a = adj + (size_t)r * N_EDGES + pb;
    for (int i = tid; i < len; i += 256) a[i] = sstage[i];
}

// ---------------------------------------------------------------------------
// Merged prep: blocks [0,6250) cast x->xb (bf16, 8 elems/thread); blocks
// [6250,6698) pre-swizzle weights into MFMA B-fragment order.
// Wfrag (layer1): as before. Wfrag2 (fused2): K=256 stacked [Wl_f;Wr_f], N=64.
__global__ void prep_kernel(const float* __restrict__ x, unsigned short* __restrict__ xb,
                            const float* __restrict__ Wl, const float* __restrict__ Wr,
                            const float* __restrict__ Wl_f, const float* __restrict__ Wr_f,
                            unsigned short* __restrict__ Wfrag, unsigned short* __restrict__ Wfrag2) {
    int bx = blockIdx.x;
    if (bx < 6250) {
        int idx = bx * 256 + threadIdx.x;
        const float4* p = (const float4*)x + (size_t)idx * 2;
        float4 a = p[0], b = p[1];
        ushort8v o;
        o[0] = f2b(a.x); o[1] = f2b(a.y); o[2] = f2b(a.z); o[3] = f2b(a.w);
        o[4] = f2b(b.x); o[5] = f2b(b.y); o[6] = f2b(b.z); o[7] = f2b(b.w);
        *(ushort8v*)(xb + (size_t)idx * 8) = o;
        return;
    }
    int idx = (bx - 6250) * 256 + threadIdx.x;     // [0, 114688)
    int j = idx & 7, lane = (idx >> 3) & 63;
    int quad = lane >> 4, l16 = lane & 15;
    if (idx < 98304) {
        int t = (idx >> 9) & 1, s = (idx >> 10) & 7, w = (idx >> 13) & 3, r = idx >> 15;
        int k = s * 32 + quad * 8 + j;
        int n = w * 32 + t * 16 + l16;
        float v = (k < 128) ? Wl[((size_t)r * 128 + k) * 128 + n]
                            : Wr[((size_t)r * 128 + (k - 128)) * 128 + n];
        Wfrag[idx] = f2b(v);
    } else {
        int i2 = idx - 98304;
        if (i2 < 16384) {
            int s = (i2 >> 9) & 7, w = i2 >> 12;
            int k = s * 32 + quad * 8 + j;
            int n = w * 16 + l16;
            float v = (k < 128) ? Wl_f[(size_t)k * 64 + n] : Wr_f[(size_t)(k - 128) * 64 + n];
            Wfrag2[i2] = f2b(v);
        }
    }
}

// ---------------------------------------------------------------------------
// FUSED layer-1: branch-free pipelined gather (ZROW sentinel) + swizzled
// 32KB LDS (5 blocks/CU) + all-relation metadata hoisted to kernel entry.
__global__ __launch_bounds__(256, 4) void fused1_kernel(
    const unsigned short* __restrict__ xb, const int* __restrict__ adj,
    const int* __restrict__ rowstart, const int* __restrict__ cnt,
    const unsigned short* __restrict__ Wfrag, const float* __restrict__ bl,
    unsigned short* __restrict__ hb) {
    __shared__ unsigned short s_x[64 * 128];
    __shared__ unsigned short s_a[64 * 128];
    int tid = threadIdx.x, wave = tid >> 6, lane = tid & 63;
    int quad = lane >> 4, l16 = lane & 15;
    int rowbase = blockIdx.x * 64;

    // hoisted metadata: all 3 relations' rowstart/cnt loads issue together
    int startv[3][4], degv[3][4];
#pragma unroll
    for (int r = 0; r < 3; r++)
#pragma unroll
        for (int g4 = 0; g4 < 4; g4++) {
            int node = rowbase + wave * 16 + g4 * 4 + quad;
            bool valid = node < N_NODES;
            startv[r][g4] = valid ? rowstart[r * N_NODES + node] : 0;
            degv[r][g4]   = valid ? cnt[r * N_NODES + node] : 0;
        }

    // stage x rows (once for all 3 relations), swizzled
#pragma unroll
    for (int it = 0; it < 4; it++) {
        int idx = tid + it * 256;
        int row = idx >> 4, c = idx & 15;
        int grow = rowbase + row;
        short8 xv = {0, 0, 0, 0, 0, 0, 0, 0};
        if (grow < N_NODES) xv = *(const short8*)(xb + (size_t)grow * 128 + c * 8);
        *(short8*)&s_x[row * 128 + SW(row, c)] = xv;
    }

    f32x4 hsum[4][2];
#pragma unroll
    for (int g = 0; g < 4; g++) { hsum[g][0] = (f32x4){0.f,0.f,0.f,0.f}; hsum[g][1] = (f32x4){0.f,0.f,0.f,0.f}; }

    for (int r = 0; r < 3; r++) {
        const int* aj = adj + (size_t)r * N_EDGES;

        int jcapv[4], idxv[4];
#pragma unroll
        for (int g4 = 0; g4 < 4; g4++) {
            jcapv[g4] = min(degv[r][g4], 16);
            idxv[g4] = (l16 < jcapv[g4]) ? aj[startv[r][g4] + l16] : ZROW;
        }
        int m = max(max(jcapv[0], jcapv[1]), max(jcapv[2], jcapv[3]));
        m = max(m, __shfl_xor(m, 16));
        m = max(m, __shfl_xor(m, 32));

        float ac[4][8];
#pragma unroll
        for (int g4 = 0; g4 < 4; g4++)
#pragma unroll
            for (int k = 0; k < 8; k++) ac[g4][k] = 0.f;

        int sb = quad * 16;
        for (int j = 0; j < m; j += 2) {
            int s0[4], s1[4];
#pragma unroll
            for (int g4 = 0; g4 < 4; g4++) {
                s0[g4] = __shfl(idxv[g4], sb + j);
                s1[g4] = __shfl(idxv[g4], sb + min(j + 1, 15));
            }
            ushort8v v0[4], v1[4];
#pragma unroll
            for (int g4 = 0; g4 < 4; g4++)
                v0[g4] = *(const ushort8v*)(xb + (size_t)s0[g4] * 128 + l16 * 8);
#pragma unroll
            for (int g4 = 0; g4 < 4; g4++)
                v1[g4] = *(const ushort8v*)(xb + (size_t)s1[g4] * 128 + l16 * 8);
#pragma unroll
            for (int g4 = 0; g4 < 4; g4++)
#pragma unroll
                for (int k = 0; k < 8; k++) ac[g4][k] += b2f(v0[g4][k]);
#pragma unroll
            for (int g4 = 0; g4 < 4; g4++)
#pragma unroll
                for (int k = 0; k < 8; k++) ac[g4][k] += b2f(v1[g4][k]);
        }
#pragma unroll
        for (int g4 = 0; g4 < 4; g4++) {
            for (int j = 16; j < degv[r][g4]; j++) {
                int s = aj[startv[r][g4] + j];
                ushort8v v = *(const ushort8v*)(xb + (size_t)s * 128 + l16 * 8);
#pragma unroll
                for (int k = 0; k < 8; k++) ac[g4][k] += b2f(v[k]);
            }
        }
#pragma unroll
        for (int g4 = 0; g4 < 4; g4++) {
            int nl = wave * 16 + g4 * 4 + quad;
            float inv = 1.0f / fmaxf((float)degv[r][g4], 1.0f);
            ushort8v o;
#pragma unroll
            for (int k = 0; k < 8; k++) o[k] = f2b(ac[g4][k] * inv);
            *(ushort8v*)&s_a[nl * 128 + SW(nl, l16)] = o;
        }
        __syncthreads();

        f32x4 acc[4][2];
#pragma unroll
        for (int g = 0; g < 4; g++) { acc[g][0] = (f32x4){0.f,0.f,0.f,0.f}; acc[g][1] = (f32x4){0.f,0.f,0.f,0.f}; }

        const unsigned short* W = Wfrag + r * 32768 + wave * 8192;
#pragma unroll
        for (int s = 0; s < 8; s++) {
            short8 bf0 = *(const short8*)(W + s * 1024 + lane * 8);
            short8 bf1 = *(const short8*)(W + s * 1024 + 512 + lane * 8);
            const unsigned short* src = (s < 4) ? s_a : s_x;
            int c16 = (s & 3) * 4 + quad;
#pragma unroll
            for (int g = 0; g < 4; g++) {
                int row = g * 16 + l16;
                short8 af = *(const short8*)&src[row * 128 + SW(row, c16)];
                acc[g][0] = __builtin_amdgcn_mfma_f32_16x16x32_bf16(af, bf0, acc[g][0], 0, 0, 0);
                acc[g][1] = __builtin_amdgcn_mfma_f32_16x16x32_bf16(af, bf1, acc[g][1], 0, 0, 0);
            }
        }

        float b0 = bl[r * 128 + wave * 32 + l16];
        float b1 = bl[r * 128 + wave * 32 + 16 + l16];
#pragma unroll
        for (int g = 0; g < 4; g++)
#pragma unroll
            for (int t = 0; t < 2; t++) {
                float bb = t ? b1 : b0;
#pragma unroll
                for (int q = 0; q < 4; q++)
                    hsum[g][t][q] += fmaxf(acc[g][t][q] + bb, 0.f) * (1.0f / 3.0f);
            }
        __syncthreads();
    }

#pragma unroll
    for (int g = 0; g < 4; g++)
#pragma unroll
        for (int t = 0; t < 2; t++) {
            int col = wave * 32 + t * 16 + l16;
#pragma unroll
            for (int q = 0; q < 4; q++) {
                int row = rowbase + g * 16 + quad * 4 + q;
                if (row < N_NODES)
                    hb[(size_t)row * 128 + col] = f2b(hsum[g][t][q]);
            }
        }
}

// ---------------------------------------------------------------------------
// FUSED layer-2 (gather-first): agg2 = mean-gather(h) into swizzled LDS,
// then out = [agg2|h](K=256) @ [Wl_f;Wr_f] + bl_f. 32KB LDS -> 5 blocks/CU.
__global__ __launch_bounds__(256, 4) void fused2_kernel(
    const unsigned short* __restrict__ hb, const int* __restrict__ adj,
    const int* __restrict__ rowstart, const int* __restrict__ cnt,
    const unsigned short* __restrict__ Wfrag2, const float* __restrict__ bl_f,
    float* __restrict__ out) {
    __shared__ unsigned short s_h[64 * 128];
    __shared__ unsigned short s_a[64 * 128];
    int tid = threadIdx.x, wave = tid >> 6, lane = tid & 63;
    int quad = lane >> 4, l16 = lane & 15;
    int rowbase = blockIdx.x * 64;

#pragma unroll
    for (int it = 0; it < 4; it++) {
        int idx = tid + it * 256;
        int row = idx >> 4, c = idx & 15;
        int grow = rowbase + row;
        short8 hv = {0, 0, 0, 0, 0, 0, 0, 0};
        if (grow < N_NODES) hv = *(const short8*)(hb + (size_t)grow * 128 + c * 8);
        *(short8*)&s_h[row * 128 + SW(row, c)] = hv;
    }

    int startv[4], degv[4], jcapv[4], idxv[4];
#pragma unroll
    for (int g4 = 0; g4 < 4; g4++) {
        int node = rowbase + wave * 16 + g4 * 4 + quad;
        bool valid = node < N_NODES;
        startv[g4] = valid ? rowstart[node] : 0;
        degv[g4]   = valid ? cnt[node] : 0;
    }
#pragma unroll
    for (int g4 = 0; g4 < 4; g4++) {
        jcapv[g4] = min(degv[g4], 16);
        idxv[g4] = (l16 < jcapv[g4]) ? adj[startv[g4] + l16] : ZROW;
    }
    int m = max(max(jcapv[0], jcapv[1]), max(jcapv[2], jcapv[3]));
    m = max(m, __shfl_xor(m, 16));
    m = max(m, __shfl_xor(m, 32));

    float ac[4][8];
#pragma unroll
    for (int g4 = 0; g4 < 4; g4++)
#pragma unroll
        for (int k = 0; k < 8; k++) ac[g4][k] = 0.f;

    int sb = quad * 16;
    for (int j = 0; j < m; j += 2) {
        int s0[4], s1[4];
#pragma unroll
        for (int g4 = 0; g4 < 4; g4++) {
            s0[g4] = __shfl(idxv[g4], sb + j);
            s1[g4] = __shfl(idxv[g4], sb + min(j + 1, 15));
        }
        ushort8v v0[4], v1[4];
#pragma unroll
        for (int g4 = 0; g4 < 4; g4++)
            v0[g4] = *(const ushort8v*)(hb + (size_t)s0[g4] * 128 + l16 * 8);
#pragma unroll
        for (int g4 = 0; g4 < 4; g4++)
            v1[g4] = *(const ushort8v*)(hb + (size_t)s1[g4] * 128 + l16 * 8);
#pragma unroll
        for (int g4 = 0; g4 < 4; g4++)
#pragma unroll
            for (int k = 0; k < 8; k++) ac[g4][k] += b2f(v0[g4][k]);
#pragma unroll
        for (int g4 = 0; g4 < 4; g4++)
#pragma unroll
            for (int k = 0; k < 8; k++) ac[g4][k] += b2f(v1[g4][k]);
    }
#pragma unroll
    for (int g4 = 0; g4 < 4; g4++) {
        for (int j = 16; j < degv[g4]; j++) {
            int s = adj[startv[g4] + j];
            ushort8v v = *(const ushort8v*)(hb + (size_t)s * 128 + l16 * 8);
#pragma unroll
            for (int k = 0; k < 8; k++) ac[g4][k] += b2f(v[k]);
        }
    }
#pragma unroll
    for (int g4 = 0; g4 < 4; g4++) {
        int nl = wave * 16 + g4 * 4 + quad;
        float inv = 1.0f / fmaxf((float)degv[g4], 1.0f);
        ushort8v o;
#pragma unroll
        for (int k = 0; k < 8; k++) o[k] = f2b(ac[g4][k] * inv);
        *(ushort8v*)&s_a[nl * 128 + SW(nl, l16)] = o;
    }
    __syncthreads();

    f32x4 acc[4];
#pragma unroll
    for (int g = 0; g < 4; g++) acc[g] = (f32x4){0.f, 0.f, 0.f, 0.f};

    const unsigned short* W = Wfrag2 + wave * 4096;
#pragma unroll
    for (int s = 0; s < 8; s++) {
        short8 bf0 = *(const short8*)(W + s * 512 + lane * 8);
        const unsigned short* src = (s < 4) ? s_a : s_h;
        int c16 = (s & 3) * 4 + quad;
#pragma unroll
        for (int g = 0; g < 4; g++) {
            int row = g * 16 + l16;
            short8 af = *(const short8*)&src[row * 128 + SW(row, c16)];
            acc[g] = __builtin_amdgcn_mfma_f32_16x16x32_bf16(af, bf0, acc[g], 0, 0, 0);
        }
    }

    float bb = bl_f[wave * 16 + l16];
    int col = wave * 16 + l16;
#pragma unroll
    for (int g = 0; g < 4; g++)
#pragma unroll
        for (int q = 0; q < 4; q++) {
            int row = rowbase + g * 16 + quad * 4 + q;
            if (row < N_NODES)
                out[(size_t)row * 64 + col] = acc[g][q] + bb;
        }
}

// ---------------------------------------------------------------------------
extern "C" void kernel_launch(void* const* d_in, const int* in_sizes, int n_in,
                              void* d_out, int out_size, void* d_ws, size_t ws_size,
                              hipStream_t stream) {
    const float* x    = (const float*)d_in[0];
    const float* Wl   = (const float*)d_in[1];
    const float* bl   = (const float*)d_in[2];
    const float* Wr   = (const float*)d_in[3];
    const float* Wl_f = (const float*)d_in[4];
    const float* bl_f = (const float*)d_in[5];
    const float* Wr_f = (const float*)d_in[6];
    const int* ei0 = (const int*)d_in[7];
    const int* ei1 = (const int*)d_in[8];
    const int* ei2 = (const int*)d_in[9];
    float* out = (float*)d_out;

    // workspace layout (offsets), total ~94 MB used
    char* ws = (char*)d_ws;
    int* cnt               = (int*)(ws);                                   // 1.2 MB
    int* bincur            = (int*)(ws + 0x128000);                        // 1.5 KB
    int* rowstart          = (int*)(ws + ((size_t)4  << 20));              // 1.2 MB
    unsigned short* Wfrag  = (unsigned short*)(ws + ((size_t)7  << 20));   // 192 KB
    unsigned short* Wfrag2 = (unsigned short*)(ws + ((size_t)15 << 19));   // 7.5MB, 32 KB
    int* adj               = (int*)(ws + ((size_t)8  << 20));              // 7.2 MB
    unsigned short* xb     = (unsigned short*)(ws + ((size_t)16 << 20));   // 25.6 MB (+ zero row)
    unsigned short* hb     = (unsigned short*)(ws + ((size_t)68 << 20));   // 25.6 MB (+ zero row)
    unsigned* bins         = (unsigned*)(ws + ((size_t)42 << 20));         // 9.4 MB

    hipMemsetAsync(bincur, 0, 3 * SUBP * sizeof(int), stream);
    hipMemsetAsync(xb + (size_t)ZROW * 128, 0, 128 * sizeof(unsigned short), stream);   // zero row
    hipMemsetAsync(hb + (size_t)ZROW * 128, 0, 128 * sizeof(unsigned short), stream);   // zero row

    bin_kernel<<<dim3(ACH, 3), 256, 0, stream>>>(ei0, ei1, ei2, bins, bincur);
    csr_kernel<<<dim3(SUBP, 3), 256, 0, stream>>>(bins, bincur, cnt, rowstart, adj);
    prep_kernel<<<6698, 256, 0, stream>>>(x, xb, Wl, Wr, Wl_f, Wr_f, Wfrag, Wfrag2);

    const int TILE_BLOCKS = (N_NODES + 63) / 64;     // 1563
    fused1_kernel<<<TILE_BLOCKS, 256, 0, stream>>>(xb, adj, rowstart, cnt, Wfrag, bl, hb);
    fused2_kernel<<<TILE_BLOCKS, 256, 0, stream>>>(hb, adj, rowstart, cnt, Wfrag2, bl_f, out);
}

// Round 13
// 275.277 us; speedup vs baseline: 1.0637x; 1.0637x over previous
//
#include <hip/hip_runtime.h>

#define N_NODES 100000
#define N_EDGES 600000
#define ZROW N_NODES         // sentinel zero-row index (xb/hb have N_NODES+1 rows)
#define LDS_STRIDE 136       // ushorts per row: 128 + 8 pad (known-good r11 layout)
#define SUBP 128             // dst sub-partitions
#define SUB_SZ 782           // nodes per sub-partition (128*782 = 100096 >= 100000)
#define ECHUNK 2048          // edges per bin_kernel block
#define ACH 293              // ceil(600000/2048)
#define BCAP 6144            // per (rel,subpart) bin capacity (mean 4687, +21 sigma)

typedef __attribute__((ext_vector_type(8))) short short8;
typedef __attribute__((ext_vector_type(4))) float f32x4;
typedef __attribute__((ext_vector_type(8))) unsigned short ushort8v;

__device__ __forceinline__ unsigned short f2b(float f) {   // fp32 -> bf16 RNE
    unsigned u = __builtin_bit_cast(unsigned, f);
    return (unsigned short)((u + 0x7fffu + ((u >> 16) & 1u)) >> 16);
}
__device__ __forceinline__ float b2f(unsigned short b) {
    return __builtin_bit_cast(float, (unsigned)b << 16);
}

// ---------------------------------------------------------------------------
// Pass A: 128-way counting sort of edges by dst sub-partition. Edge packed
// into 4B: src (17b) | local-dst (10b, <782). LDS-staged compaction ->
// line-granular global writes into per-(rel,subpart) bins.
__global__ __launch_bounds__(256) void bin_kernel(const int* __restrict__ e0,
                                                  const int* __restrict__ e1,
                                                  const int* __restrict__ e2,
                                                  unsigned* __restrict__ bins,
                                                  int* __restrict__ bincur) {
    int r = blockIdx.y;
    const int* ei = (r == 0) ? e0 : (r == 1 ? e1 : e2);
    int base = blockIdx.x * ECHUNK;
    int nhere = min(ECHUNK, N_EDGES - base);
    __shared__ int lhist[SUBP], lstart[SUBP], lcur[SUBP], gbase[SUBP];
    __shared__ unsigned led[ECHUNK];
    __shared__ unsigned char lbkt[ECHUNK];
    int tid = threadIdx.x;
    for (int i = tid; i < SUBP; i += 256) { lhist[i] = 0; lcur[i] = 0; }
    __syncthreads();

    unsigned pk[8]; int bn[8];
#pragma unroll
    for (int k = 0; k < 8; k++) {
        int i = tid + k * 256;
        bn[k] = -1;
        if (i < nhere) {
            int e = base + i;
            int s = ei[e], d = ei[N_EDGES + e];
            int b = d / SUB_SZ;
            int ld = d - b * SUB_SZ;
            pk[k] = (unsigned)s | ((unsigned)ld << 17);
            bn[k] = b;
            atomicAdd(&lhist[b], 1);
        }
    }
    __syncthreads();
    if (tid == 0) {
        int run = 0;
        for (int b = 0; b < SUBP; b++) { lstart[b] = run; run += lhist[b]; }
    }
    __syncthreads();
#pragma unroll
    for (int k = 0; k < 8; k++) {
        if (bn[k] >= 0) {
            int slot = atomicAdd(&lcur[bn[k]], 1);
            int p = lstart[bn[k]] + slot;
            led[p] = pk[k];
            lbkt[p] = (unsigned char)bn[k];
        }
    }
    if (tid < SUBP) gbase[tid] = atomicAdd(&bincur[r * SUBP + tid], lhist[tid]);
    __syncthreads();
    for (int i = tid; i < nhere; i += 256) {
        int b = lbkt[i];
        int dstidx = gbase[b] + (i - lstart[b]);
        if (dstidx < BCAP)   // safety clamp: drop (never fault) on overflow
            bins[(size_t)(r * SUBP + b) * BCAP + dstidx] = led[i];
    }
}

// ---------------------------------------------------------------------------
// Consolidated CSR build: one block per (rel,subpart). Inline pbase prefix
// (wave 3) + LDS histogram -> in-LDS scan -> cnt/rowstart -> LDS-cursor fill
// -> coalesced adj streaming.
__global__ __launch_bounds__(256) void csr_kernel(const unsigned* __restrict__ bins,
                                                  const int* __restrict__ bincur,
                                                  int* __restrict__ cnt,
                                                  int* __restrict__ rowstart,
                                                  int* __restrict__ adj) {
    int p = blockIdx.x, r = blockIdx.y;
    int n0 = p * SUB_SZ;
    int nodes = min(SUB_SZ, N_NODES - n0);
    __shared__ int hist[SUB_SZ];
    __shared__ int sstage[BCAP];
    __shared__ int wsums[4];
    __shared__ int s_pb;
    int tid = threadIdx.x, lane = tid & 63, wid = tid >> 6;
    for (int i = tid; i < SUB_SZ; i += 256) hist[i] = 0;
    if (wid == 3) {   // inline prefix over this relation's partition totals
        int v0 = (lane < p) ? bincur[r * SUBP + lane] : 0;
        int v1 = (lane + 64 < p) ? bincur[r * SUBP + 64 + lane] : 0;
        int s = v0 + v1;
#pragma unroll
        for (int off = 1; off < 64; off <<= 1) s += __shfl_xor(s, off);
        if (lane == 0) s_pb = s;
    }
    __syncthreads();
    int len = min(bincur[r * SUBP + p], BCAP);
    const unsigned* b = bins + (size_t)(r * SUBP + p) * BCAP;
    for (int i = tid; i < len; i += 256) atomicAdd(&hist[b[i] >> 17], 1);
    __syncthreads();
    int base4 = tid * 4;
    int v[4]; int tsum = 0;
#pragma unroll
    for (int k = 0; k < 4; k++) {
        int i = base4 + k;
        v[k] = (i < SUB_SZ) ? hist[i] : 0;
        tsum += v[k];
    }
    for (int i = tid; i < nodes; i += 256) cnt[r * N_NODES + n0 + i] = hist[i];
    int incl = tsum;
#pragma unroll
    for (int off = 1; off < 64; off <<= 1) {
        int t = __shfl_up(incl, off);
        if (lane >= off) incl += t;
    }
    if (lane == 63) wsums[wid] = incl;
    __syncthreads();
    if (tid == 0) { int run = 0; for (int w = 0; w < 4; w++) { int t = wsums[w]; wsums[w] = run; run += t; } }
    __syncthreads();
    int excl = incl - tsum + wsums[wid];
    int pb = s_pb;
    int run = excl;
#pragma unroll
    for (int k = 0; k < 4; k++) {
        int i = base4 + k;
        if (i < SUB_SZ) {
            if (i < nodes) rowstart[r * N_NODES + n0 + i] = pb + run;
            hist[i] = run;              // local cursor seed
        }
        run += v[k];
    }
    __syncthreads();
    for (int i = tid; i < len; i += 256) {
        unsigned vv = b[i];
        int pos = atomicAdd(&hist[vv >> 17], 1);
        if (pos < BCAP) sstage[pos] = (int)(vv & 0x1FFFFu);
    }
    __syncthreads();
    int* a = adj + (size_t)r * N_EDGES + pb;
    for (int i = tid; i < len; i += 256) a[i] = sstage[i];
}

// ---------------------------------------------------------------------------
// Merged prep: blocks [0,6250) cast x->xb (bf16, 8 elems/thread); blocks
// [6250,6698) pre-swizzle weights into MFMA B-fragment order.
// Wfrag (layer1): as before. Wfrag2 (fused2): K=256 stacked [Wl_f;Wr_f], N=64.
__global__ void prep_kernel(const float* __restrict__ x, unsigned short* __restrict__ xb,
                            const float* __restrict__ Wl, const float* __restrict__ Wr,
                            const float* __restrict__ Wl_f, const float* __restrict__ Wr_f,
                            unsigned short* __restrict__ Wfrag, unsigned short* __restrict__ Wfrag2) {
    int bx = blockIdx.x;
    if (bx < 6250) {
        int idx = bx * 256 + threadIdx.x;
        const float4* p = (const float4*)x + (size_t)idx * 2;
        float4 a = p[0], b = p[1];
        ushort8v o;
        o[0] = f2b(a.x); o[1] = f2b(a.y); o[2] = f2b(a.z); o[3] = f2b(a.w);
        o[4] = f2b(b.x); o[5] = f2b(b.y); o[6] = f2b(b.z); o[7] = f2b(b.w);
        *(ushort8v*)(xb + (size_t)idx * 8) = o;
        return;
    }
    int idx = (bx - 6250) * 256 + threadIdx.x;     // [0, 114688)
    int j = idx & 7, lane = (idx >> 3) & 63;
    int quad = lane >> 4, l16 = lane & 15;
    if (idx < 98304) {
        int t = (idx >> 9) & 1, s = (idx >> 10) & 7, w = (idx >> 13) & 3, r = idx >> 15;
        int k = s * 32 + quad * 8 + j;
        int n = w * 32 + t * 16 + l16;
        float v = (k < 128) ? Wl[((size_t)r * 128 + k) * 128 + n]
                            : Wr[((size_t)r * 128 + (k - 128)) * 128 + n];
        Wfrag[idx] = f2b(v);
    } else {
        int i2 = idx - 98304;
        if (i2 < 16384) {
            int s = (i2 >> 9) & 7, w = i2 >> 12;
            int k = s * 32 + quad * 8 + j;
            int n = w * 16 + l16;
            float v = (k < 128) ? Wl_f[(size_t)k * 64 + n] : Wr_f[(size_t)(k - 128) * 64 + n];
            Wfrag2[i2] = f2b(v);
        }
    }
}

// ---------------------------------------------------------------------------
// FUSED layer-1: branch-free pipelined gather (ZROW sentinel), r11 structure
// (per-relation metadata, padded LDS) + LDS-staged coalesced hb epilogue.
__global__ __launch_bounds__(256, 4) void fused1_kernel(
    const unsigned short* __restrict__ xb, const int* __restrict__ adj,
    const int* __restrict__ rowstart, const int* __restrict__ cnt,
    const unsigned short* __restrict__ Wfrag, const float* __restrict__ bl,
    unsigned short* __restrict__ hb) {
    __shared__ unsigned short s_x[64 * LDS_STRIDE];
    __shared__ unsigned short s_a[64 * LDS_STRIDE];
    int tid = threadIdx.x, wave = tid >> 6, lane = tid & 63;
    int quad = lane >> 4, l16 = lane & 15;
    int rowbase = blockIdx.x * 64;

#pragma unroll
    for (int it = 0; it < 4; it++) {
        int idx = tid + it * 256;
        int row = idx >> 4, c = idx & 15;
        int grow = rowbase + row;
        short8 xv = {0, 0, 0, 0, 0, 0, 0, 0};
        if (grow < N_NODES) xv = *(const short8*)(xb + (size_t)grow * 128 + c * 8);
        *(short8*)&s_x[row * LDS_STRIDE + c * 8] = xv;
    }

    f32x4 hsum[4][2];
#pragma unroll
    for (int g = 0; g < 4; g++) { hsum[g][0] = (f32x4){0.f,0.f,0.f,0.f}; hsum[g][1] = (f32x4){0.f,0.f,0.f,0.f}; }

    for (int r = 0; r < 3; r++) {
        const int* rs = rowstart + r * N_NODES;
        const int* ct = cnt + r * N_NODES;
        const int* aj = adj + (size_t)r * N_EDGES;

        int startv[4], degv[4], jcapv[4], idxv[4];
#pragma unroll
        for (int g4 = 0; g4 < 4; g4++) {
            int node = rowbase + wave * 16 + g4 * 4 + quad;
            bool valid = node < N_NODES;
            startv[g4] = valid ? rs[node] : 0;
            degv[g4]   = valid ? ct[node] : 0;
        }
#pragma unroll
        for (int g4 = 0; g4 < 4; g4++) {
            jcapv[g4] = min(degv[g4], 16);
            idxv[g4] = (l16 < jcapv[g4]) ? aj[startv[g4] + l16] : ZROW;
        }
        int m = max(max(jcapv[0], jcapv[1]), max(jcapv[2], jcapv[3]));
        m = max(m, __shfl_xor(m, 16));
        m = max(m, __shfl_xor(m, 32));

        float ac[4][8];
#pragma unroll
        for (int g4 = 0; g4 < 4; g4++)
#pragma unroll
            for (int k = 0; k < 8; k++) ac[g4][k] = 0.f;

        int sb = quad * 16;
        for (int j = 0; j < m; j += 2) {
            int s0[4], s1[4];
#pragma unroll
            for (int g4 = 0; g4 < 4; g4++) {
                s0[g4] = __shfl(idxv[g4], sb + j);
                s1[g4] = __shfl(idxv[g4], sb + min(j + 1, 15));
            }
            ushort8v v0[4], v1[4];
#pragma unroll
            for (int g4 = 0; g4 < 4; g4++)
                v0[g4] = *(const ushort8v*)(xb + (size_t)s0[g4] * 128 + l16 * 8);
#pragma unroll
            for (int g4 = 0; g4 < 4; g4++)
                v1[g4] = *(const ushort8v*)(xb + (size_t)s1[g4] * 128 + l16 * 8);
#pragma unroll
            for (int g4 = 0; g4 < 4; g4++)
#pragma unroll
                for (int k = 0; k < 8; k++) ac[g4][k] += b2f(v0[g4][k]);
#pragma unroll
            for (int g4 = 0; g4 < 4; g4++)
#pragma unroll
                for (int k = 0; k < 8; k++) ac[g4][k] += b2f(v1[g4][k]);
        }
#pragma unroll
        for (int g4 = 0; g4 < 4; g4++) {
            for (int j = 16; j < degv[g4]; j++) {
                int s = aj[startv[g4] + j];
                ushort8v v = *(const ushort8v*)(xb + (size_t)s * 128 + l16 * 8);
#pragma unroll
                for (int k = 0; k < 8; k++) ac[g4][k] += b2f(v[k]);
            }
        }
#pragma unroll
        for (int g4 = 0; g4 < 4; g4++) {
            int nl = wave * 16 + g4 * 4 + quad;
            float inv = 1.0f / fmaxf((float)degv[g4], 1.0f);
            ushort8v o;
#pragma unroll
            for (int k = 0; k < 8; k++) o[k] = f2b(ac[g4][k] * inv);
            *(ushort8v*)&s_a[nl * LDS_STRIDE + l16 * 8] = o;
        }
        __syncthreads();

        f32x4 acc[4][2];
#pragma unroll
        for (int g = 0; g < 4; g++) { acc[g][0] = (f32x4){0.f,0.f,0.f,0.f}; acc[g][1] = (f32x4){0.f,0.f,0.f,0.f}; }

        const unsigned short* W = Wfrag + r * 32768 + wave * 8192;
#pragma unroll
        for (int s = 0; s < 8; s++) {
            short8 bf0 = *(const short8*)(W + s * 1024 + lane * 8);
            short8 bf1 = *(const short8*)(W + s * 1024 + 512 + lane * 8);
            const unsigned short* src = (s < 4) ? s_a : s_x;
            int ko = (s & 3) * 32 + quad * 8;
#pragma unroll
            for (int g = 0; g < 4; g++) {
                short8 af = *(const short8*)&src[(g * 16 + l16) * LDS_STRIDE + ko];
                acc[g][0] = __builtin_amdgcn_mfma_f32_16x16x32_bf16(af, bf0, acc[g][0], 0, 0, 0);
                acc[g][1] = __builtin_amdgcn_mfma_f32_16x16x32_bf16(af, bf1, acc[g][1], 0, 0, 0);
            }
        }

        float b0 = bl[r * 128 + wave * 32 + l16];
        float b1 = bl[r * 128 + wave * 32 + 16 + l16];
#pragma unroll
        for (int g = 0; g < 4; g++)
#pragma unroll
            for (int t = 0; t < 2; t++) {
                float bb = t ? b1 : b0;
#pragma unroll
                for (int q = 0; q < 4; q++)
                    hsum[g][t][q] += fmaxf(acc[g][t][q] + bb, 0.f) * (1.0f / 3.0f);
            }
        __syncthreads();
    }

    // epilogue: hsum -> s_a (bf16 fragments), then coalesced 16B hb stores
#pragma unroll
    for (int g = 0; g < 4; g++)
#pragma unroll
        for (int t = 0; t < 2; t++) {
            int col = wave * 32 + t * 16 + l16;
#pragma unroll
            for (int q = 0; q < 4; q++) {
                int row = g * 16 + quad * 4 + q;
                s_a[row * LDS_STRIDE + col] = f2b(hsum[g][t][q]);
            }
        }
    __syncthreads();
#pragma unroll
    for (int it = 0; it < 4; it++) {
        int idx = tid + it * 256;
        int row = idx >> 4, c = idx & 15;
        int grow = rowbase + row;
        if (grow < N_NODES)
            *(ushort8v*)(hb + (size_t)grow * 128 + c * 8) =
                *(const ushort8v*)&s_a[row * LDS_STRIDE + c * 8];
    }
}

// ---------------------------------------------------------------------------
// FUSED layer-2 (gather-first): agg2 = mean-gather(h) into LDS (branch-free
// slot gather from hb rows), then out = [agg2|h](K=256) @ [Wl_f;Wr_f] + bl_f.
__global__ __launch_bounds__(256, 4) void fused2_kernel(
    const unsigned short* __restrict__ hb, const int* __restrict__ adj,
    const int* __restrict__ rowstart, const int* __restrict__ cnt,
    const unsigned short* __restrict__ Wfrag2, const float* __restrict__ bl_f,
    float* __restrict__ out) {
    __shared__ unsigned short s_h[64 * LDS_STRIDE];
    __shared__ unsigned short s_a[64 * LDS_STRIDE];
    int tid = threadIdx.x, wave = tid >> 6, lane = tid & 63;
    int quad = lane >> 4, l16 = lane & 15;
    int rowbase = blockIdx.x * 64;

#pragma unroll
    for (int it = 0; it < 4; it++) {
        int idx = tid + it * 256;
        int row = idx >> 4, c = idx & 15;
        int grow = rowbase + row;
        short8 hv = {0, 0, 0, 0, 0, 0, 0, 0};
        if (grow < N_NODES) hv = *(const short8*)(hb + (size_t)grow * 128 + c * 8);
        *(short8*)&s_h[row * LDS_STRIDE + c * 8] = hv;
    }

    int startv[4], degv[4], jcapv[4], idxv[4];
#pragma unroll
    for (int g4 = 0; g4 < 4; g4++) {
        int node = rowbase + wave * 16 + g4 * 4 + quad;
        bool valid = node < N_NODES;
        startv[g4] = valid ? rowstart[node] : 0;
        degv[g4]   = valid ? cnt[node] : 0;
    }
#pragma unroll
    for (int g4 = 0; g4 < 4; g4++) {
        jcapv[g4] = min(degv[g4], 16);
        idxv[g4] = (l16 < jcapv[g4]) ? adj[startv[g4] + l16] : ZROW;
    }
    int m = max(max(jcapv[0], jcapv[1]), max(jcapv[2], jcapv[3]));
    m = max(m, __shfl_xor(m, 16));
    m = max(m, __shfl_xor(m, 32));

    float ac[4][8];
#pragma unroll
    for (int g4 = 0; g4 < 4; g4++)
#pragma unroll
        for (int k = 0; k < 8; k++) ac[g4][k] = 0.f;

    int sb = quad * 16;
    for (int j = 0; j < m; j += 2) {
        int s0[4], s1[4];
#pragma unroll
        for (int g4 = 0; g4 < 4; g4++) {
            s0[g4] = __shfl(idxv[g4], sb + j);
            s1[g4] = __shfl(idxv[g4], sb + min(j + 1, 15));
        }
        ushort8v v0[4], v1[4];
#pragma unroll
        for (int g4 = 0; g4 < 4; g4++)
            v0[g4] = *(const ushort8v*)(hb + (size_t)s0[g4] * 128 + l16 * 8);
#pragma unroll
        for (int g4 = 0; g4 < 4; g4++)
            v1[g4] = *(const ushort8v*)(hb + (size_t)s1[g4] * 128 + l16 * 8);
#pragma unroll
        for (int g4 = 0; g4 < 4; g4++)
#pragma unroll
            for (int k = 0; k < 8; k++) ac[g4][k] += b2f(v0[g4][k]);
#pragma unroll
        for (int g4 = 0; g4 < 4; g4++)
#pragma unroll
            for (int k = 0; k < 8; k++) ac[g4][k] += b2f(v1[g4][k]);
    }
#pragma unroll
    for (int g4 = 0; g4 < 4; g4++) {
        for (int j = 16; j < degv[g4]; j++) {
            int s = adj[startv[g4] + j];
            ushort8v v = *(const ushort8v*)(hb + (size_t)s * 128 + l16 * 8);
#pragma unroll
            for (int k = 0; k < 8; k++) ac[g4][k] += b2f(v[k]);
        }
    }
#pragma unroll
    for (int g4 = 0; g4 < 4; g4++) {
        int nl = wave * 16 + g4 * 4 + quad;
        float inv = 1.0f / fmaxf((float)degv[g4], 1.0f);
        ushort8v o;
#pragma unroll
        for (int k = 0; k < 8; k++) o[k] = f2b(ac[g4][k] * inv);
        *(ushort8v*)&s_a[nl * LDS_STRIDE + l16 * 8] = o;
    }
    __syncthreads();

    f32x4 acc[4];
#pragma unroll
    for (int g = 0; g < 4; g++) acc[g] = (f32x4){0.f, 0.f, 0.f, 0.f};

    const unsigned short* W = Wfrag2 + wave * 4096;
#pragma unroll
    for (int s = 0; s < 8; s++) {
        short8 bf0 = *(const short8*)(W + s * 512 + lane * 8);
        const unsigned short* src = (s < 4) ? s_a : s_h;
        int ko = (s & 3) * 32 + quad * 8;
#pragma unroll
        for (int g = 0; g < 4; g++) {
            short8 af = *(const short8*)&src[(g * 16 + l16) * LDS_STRIDE + ko];
            acc[g] = __builtin_amdgcn_mfma_f32_16x16x32_bf16(af, bf0, acc[g], 0, 0, 0);
        }
    }

    float bb = bl_f[wave * 16 + l16];
    int col = wave * 16 + l16;
#pragma unroll
    for (int g = 0; g < 4; g++)
#pragma unroll
        for (int q = 0; q < 4; q++) {
            int row = rowbase + g * 16 + quad * 4 + q;
            if (row < N_NODES)
                out[(size_t)row * 64 + col] = acc[g][q] + bb;
        }
}

// ---------------------------------------------------------------------------
extern "C" void kernel_launch(void* const* d_in, const int* in_sizes, int n_in,
                              void* d_out, int out_size, void* d_ws, size_t ws_size,
                              hipStream_t stream) {
    const float* x    = (const float*)d_in[0];
    const float* Wl   = (const float*)d_in[1];
    const float* bl   = (const float*)d_in[2];
    const float* Wr   = (const float*)d_in[3];
    const float* Wl_f = (const float*)d_in[4];
    const float* bl_f = (const float*)d_in[5];
    const float* Wr_f = (const float*)d_in[6];
    const int* ei0 = (const int*)d_in[7];
    const int* ei1 = (const int*)d_in[8];
    const int* ei2 = (const int*)d_in[9];
    float* out = (float*)d_out;

    // workspace layout (offsets), total ~94 MB used
    char* ws = (char*)d_ws;
    int* cnt               = (int*)(ws);                                   // 1.2 MB
    int* bincur            = (int*)(ws + 0x128000);                        // 1.5 KB
    int* rowstart          = (int*)(ws + ((size_t)4  << 20));              // 1.2 MB
    unsigned short* Wfrag  = (unsigned short*)(ws + ((size_t)7  << 20));   // 192 KB
    unsigned short* Wfrag2 = (unsigned short*)(ws + ((size_t)15 << 19));   // 7.5MB, 32 KB
    int* adj               = (int*)(ws + ((size_t)8  << 20));              // 7.2 MB
    unsigned short* xb     = (unsigned short*)(ws + ((size_t)16 << 20));   // 25.6 MB (+ zero row)
    unsigned short* hb     = (unsigned short*)(ws + ((size_t)68 << 20));   // 25.6 MB (+ zero row)
    unsigned* bins         = (unsigned*)(ws + ((size_t)42 << 20));         // 9.4 MB

    hipMemsetAsync(bincur, 0, 3 * SUBP * sizeof(int), stream);
    hipMemsetAsync(xb + (size_t)ZROW * 128, 0, 128 * sizeof(unsigned short), stream);   // zero row
    hipMemsetAsync(hb + (size_t)ZROW * 128, 0, 128 * sizeof(unsigned short), stream);   // zero row

    bin_kernel<<<dim3(ACH, 3), 256, 0, stream>>>(ei0, ei1, ei2, bins, bincur);
    csr_kernel<<<dim3(SUBP, 3), 256, 0, stream>>>(bins, bincur, cnt, rowstart, adj);
    prep_kernel<<<6698, 256, 0, stream>>>(x, xb, Wl, Wr, Wl_f, Wr_f, Wfrag, Wfrag2);

    const int TILE_BLOCKS = (N_NODES + 63) / 64;     // 1563
    fused1_kernel<<<TILE_BLOCKS, 256, 0, stream>>>(xb, adj, rowstart, cnt, Wfrag, bl, hb);
    fused2_kernel<<<TILE_BLOCKS, 256, 0, stream>>>(hb, adj, rowstart, cnt, Wfrag2, bl_f, out);
}

// Round 14
// 264.284 us; speedup vs baseline: 1.1080x; 1.0416x over previous
//
#include <hip/hip_runtime.h>

#define N_NODES 100000
#define N_EDGES 600000
#define ZROW N_NODES         // sentinel zero-row index (xb/hb have N_NODES+1 rows)
#define SUBP 128             // dst sub-partitions
#define SUB_SZ 782           // nodes per sub-partition (128*782 = 100096 >= 100000)
#define ECHUNK 2048          // edges per bin block
#define ACH 293              // ceil(600000/2048)
#define BINBLK (3 * ACH)     // 879 bin blocks in merged front-end kernel
#define BCAP 6144            // per (rel,subpart) bin capacity (mean 4687, +21 sigma)
// LDS tiles: stride 128 ushorts (256B), XOR-swizzled 16B units -> 32768 B per
// kernel = 5 blocks/CU (163840/32768). Swizzle correctness-proven in r12;
// r12's regression was metadata-hoist spills (FETCH/WRITE ballooned), not SW.
#define SW(row, c16) ((((c16) ^ ((row) & 7)) << 3))

typedef __attribute__((ext_vector_type(8))) short short8;
typedef __attribute__((ext_vector_type(4))) float f32x4;
typedef __attribute__((ext_vector_type(8))) unsigned short ushort8v;

__device__ __forceinline__ unsigned short f2b(float f) {   // fp32 -> bf16 RNE
    unsigned u = __builtin_bit_cast(unsigned, f);
    return (unsigned short)((u + 0x7fffu + ((u >> 16) & 1u)) >> 16);
}
__device__ __forceinline__ float b2f(unsigned short b) {
    return __builtin_bit_cast(float, (unsigned)b << 16);
}

// ---------------------------------------------------------------------------
// Merged front-end: blocks [0,879) = 128-way edge binning (3 rels x 293
// chunks); blocks [879, 879+6250) = x->bf16 cast; rest = weight pre-swizzle.
__global__ __launch_bounds__(256) void binprep_kernel(
    const int* __restrict__ e0, const int* __restrict__ e1, const int* __restrict__ e2,
    unsigned* __restrict__ bins, int* __restrict__ bincur,
    const float* __restrict__ x, unsigned short* __restrict__ xb,
    const float* __restrict__ Wl, const float* __restrict__ Wr,
    const float* __restrict__ Wl_f, const float* __restrict__ Wr_f,
    unsigned short* __restrict__ Wfrag, unsigned short* __restrict__ Wfrag2) {
    int bx = blockIdx.x;
    int tid = threadIdx.x;
    if (bx < BINBLK) {
        // ---- bin part: counting sort of edges by dst sub-partition ----
        int r = bx / ACH, chunk = bx % ACH;
        const int* ei = (r == 0) ? e0 : (r == 1 ? e1 : e2);
        int base = chunk * ECHUNK;
        int nhere = min(ECHUNK, N_EDGES - base);
        __shared__ int lhist[SUBP], lstart[SUBP], lcur[SUBP], gbase[SUBP];
        __shared__ unsigned led[ECHUNK];
        __shared__ unsigned char lbkt[ECHUNK];
        for (int i = tid; i < SUBP; i += 256) { lhist[i] = 0; lcur[i] = 0; }
        __syncthreads();
        unsigned pk[8]; int bn[8];
#pragma unroll
        for (int k = 0; k < 8; k++) {
            int i = tid + k * 256;
            bn[k] = -1;
            if (i < nhere) {
                int e = base + i;
                int s = ei[e], d = ei[N_EDGES + e];
                int b = d / SUB_SZ;
                int ld = d - b * SUB_SZ;
                pk[k] = (unsigned)s | ((unsigned)ld << 17);
                bn[k] = b;
                atomicAdd(&lhist[b], 1);
            }
        }
        __syncthreads();
        if (tid == 0) {
            int run = 0;
            for (int b = 0; b < SUBP; b++) { lstart[b] = run; run += lhist[b]; }
        }
        __syncthreads();
#pragma unroll
        for (int k = 0; k < 8; k++) {
            if (bn[k] >= 0) {
                int slot = atomicAdd(&lcur[bn[k]], 1);
                int p = lstart[bn[k]] + slot;
                led[p] = pk[k];
                lbkt[p] = (unsigned char)bn[k];
            }
        }
        if (tid < SUBP) gbase[tid] = atomicAdd(&bincur[r * SUBP + tid], lhist[tid]);
        __syncthreads();
        for (int i = tid; i < nhere; i += 256) {
            int b = lbkt[i];
            int dstidx = gbase[b] + (i - lstart[b]);
            if (dstidx < BCAP)   // safety clamp: drop (never fault) on overflow
                bins[(size_t)(r * SUBP + b) * BCAP + dstidx] = led[i];
        }
        return;
    }
    int pbx = bx - BINBLK;
    if (pbx < 6250) {
        // ---- xcast part ----
        int idx = pbx * 256 + tid;
        const float4* p = (const float4*)x + (size_t)idx * 2;
        float4 a = p[0], b = p[1];
        ushort8v o;
        o[0] = f2b(a.x); o[1] = f2b(a.y); o[2] = f2b(a.z); o[3] = f2b(a.w);
        o[4] = f2b(b.x); o[5] = f2b(b.y); o[6] = f2b(b.z); o[7] = f2b(b.w);
        *(ushort8v*)(xb + (size_t)idx * 8) = o;
        return;
    }
    // ---- wprep part ----
    int idx = (pbx - 6250) * 256 + tid;            // [0, 114688)
    int j = idx & 7, lane = (idx >> 3) & 63;
    int quad = lane >> 4, l16 = lane & 15;
    if (idx < 98304) {
        int t = (idx >> 9) & 1, s = (idx >> 10) & 7, w = (idx >> 13) & 3, r = idx >> 15;
        int k = s * 32 + quad * 8 + j;
        int n = w * 32 + t * 16 + l16;
        float v = (k < 128) ? Wl[((size_t)r * 128 + k) * 128 + n]
                            : Wr[((size_t)r * 128 + (k - 128)) * 128 + n];
        Wfrag[idx] = f2b(v);
    } else {
        int i2 = idx - 98304;
        if (i2 < 16384) {
            int s = (i2 >> 9) & 7, w = i2 >> 12;
            int k = s * 32 + quad * 8 + j;
            int n = w * 16 + l16;
            float v = (k < 128) ? Wl_f[(size_t)k * 64 + n] : Wr_f[(size_t)(k - 128) * 64 + n];
            Wfrag2[i2] = f2b(v);
        }
    }
}

// ---------------------------------------------------------------------------
// Consolidated CSR build: one block per (rel,subpart). Inline pbase prefix
// (wave 3) + LDS histogram -> in-LDS scan -> cnt/rowstart -> LDS-cursor fill
// -> coalesced adj streaming.
__global__ __launch_bounds__(256) void csr_kernel(const unsigned* __restrict__ bins,
                                                  const int* __restrict__ bincur,
                                                  int* __restrict__ cnt,
                                                  int* __restrict__ rowstart,
                                                  int* __restrict__ adj) {
    int p = blockIdx.x, r = blockIdx.y;
    int n0 = p * SUB_SZ;
    int nodes = min(SUB_SZ, N_NODES - n0);
    __shared__ int hist[SUB_SZ];
    __shared__ int sstage[BCAP];
    __shared__ int wsums[4];
    __shared__ int s_pb;
    int tid = threadIdx.x, lane = tid & 63, wid = tid >> 6;
    for (int i = tid; i < SUB_SZ; i += 256) hist[i] = 0;
    if (wid == 3) {   // inline prefix over this relation's partition totals
        int v0 = (lane < p) ? bincur[r * SUBP + lane] : 0;
        int v1 = (lane + 64 < p) ? bincur[r * SUBP + 64 + lane] : 0;
        int s = v0 + v1;
#pragma unroll
        for (int off = 1; off < 64; off <<= 1) s += __shfl_xor(s, off);
        if (lane == 0) s_pb = s;
    }
    __syncthreads();
    int len = min(bincur[r * SUBP + p], BCAP);
    const unsigned* b = bins + (size_t)(r * SUBP + p) * BCAP;
    for (int i = tid; i < len; i += 256) atomicAdd(&hist[b[i] >> 17], 1);
    __syncthreads();
    int base4 = tid * 4;
    int v[4]; int tsum = 0;
#pragma unroll
    for (int k = 0; k < 4; k++) {
        int i = base4 + k;
        v[k] = (i < SUB_SZ) ? hist[i] : 0;
        tsum += v[k];
    }
    for (int i = tid; i < nodes; i += 256) cnt[r * N_NODES + n0 + i] = hist[i];
    int incl = tsum;
#pragma unroll
    for (int off = 1; off < 64; off <<= 1) {
        int t = __shfl_up(incl, off);
        if (lane >= off) incl += t;
    }
    if (lane == 63) wsums[wid] = incl;
    __syncthreads();
    if (tid == 0) { int run = 0; for (int w = 0; w < 4; w++) { int t = wsums[w]; wsums[w] = run; run += t; } }
    __syncthreads();
    int excl = incl - tsum + wsums[wid];
    int pb = s_pb;
    int run = excl;
#pragma unroll
    for (int k = 0; k < 4; k++) {
        int i = base4 + k;
        if (i < SUB_SZ) {
            if (i < nodes) rowstart[r * N_NODES + n0 + i] = pb + run;
            hist[i] = run;              // local cursor seed
        }
        run += v[k];
    }
    __syncthreads();
    for (int i = tid; i < len; i += 256) {
        unsigned vv = b[i];
        int pos = atomicAdd(&hist[vv >> 17], 1);
        if (pos < BCAP) sstage[pos] = (int)(vv & 0x1FFFFu);
    }
    __syncthreads();
    int* a = adj + (size_t)r * N_EDGES + pb;
    for (int i = tid; i < len; i += 256) a[i] = sstage[i];
}

// ---------------------------------------------------------------------------
// FUSED layer-1: branch-free pipelined gather (ZROW sentinel), per-relation
// metadata (r11 register-light form), swizzled 32KB LDS (5 blocks/CU),
// direct-scatter hb epilogue (r11 known-good).
__global__ __launch_bounds__(256, 4) void fused1_kernel(
    const unsigned short* __restrict__ xb, const int* __restrict__ adj,
    const int* __restrict__ rowstart, const int* __restrict__ cnt,
    const unsigned short* __restrict__ Wfrag, const float* __restrict__ bl,
    unsigned short* __restrict__ hb) {
    __shared__ unsigned short s_x[64 * 128];
    __shared__ unsigned short s_a[64 * 128];
    int tid = threadIdx.x, wave = tid >> 6, lane = tid & 63;
    int quad = lane >> 4, l16 = lane & 15;
    int rowbase = blockIdx.x * 64;

#pragma unroll
    for (int it = 0; it < 4; it++) {
        int idx = tid + it * 256;
        int row = idx >> 4, c = idx & 15;
        int grow = rowbase + row;
        short8 xv = {0, 0, 0, 0, 0, 0, 0, 0};
        if (grow < N_NODES) xv = *(const short8*)(xb + (size_t)grow * 128 + c * 8);
        *(short8*)&s_x[row * 128 + SW(row, c)] = xv;
    }

    f32x4 hsum[4][2];
#pragma unroll
    for (int g = 0; g < 4; g++) { hsum[g][0] = (f32x4){0.f,0.f,0.f,0.f}; hsum[g][1] = (f32x4){0.f,0.f,0.f,0.f}; }

    for (int r = 0; r < 3; r++) {
        const int* rs = rowstart + r * N_NODES;
        const int* ct = cnt + r * N_NODES;
        const int* aj = adj + (size_t)r * N_EDGES;

        int startv[4], degv[4], jcapv[4], idxv[4];
#pragma unroll
        for (int g4 = 0; g4 < 4; g4++) {
            int node = rowbase + wave * 16 + g4 * 4 + quad;
            bool valid = node < N_NODES;
            startv[g4] = valid ? rs[node] : 0;
            degv[g4]   = valid ? ct[node] : 0;
        }
#pragma unroll
        for (int g4 = 0; g4 < 4; g4++) {
            jcapv[g4] = min(degv[g4], 16);
            idxv[g4] = (l16 < jcapv[g4]) ? aj[startv[g4] + l16] : ZROW;
        }
        int m = max(max(jcapv[0], jcapv[1]), max(jcapv[2], jcapv[3]));
        m = max(m, __shfl_xor(m, 16));
        m = max(m, __shfl_xor(m, 32));

        float ac[4][8];
#pragma unroll
        for (int g4 = 0; g4 < 4; g4++)
#pragma unroll
            for (int k = 0; k < 8; k++) ac[g4][k] = 0.f;

        int sb = quad * 16;
        for (int j = 0; j < m; j += 2) {
            int s0[4], s1[4];
#pragma unroll
            for (int g4 = 0; g4 < 4; g4++) {
                s0[g4] = __shfl(idxv[g4], sb + j);
                s1[g4] = __shfl(idxv[g4], sb + min(j + 1, 15));
            }
            ushort8v v0[4], v1[4];
#pragma unroll
            for (int g4 = 0; g4 < 4; g4++)
                v0[g4] = *(const ushort8v*)(xb + (size_t)s0[g4] * 128 + l16 * 8);
#pragma unroll
            for (int g4 = 0; g4 < 4; g4++)
                v1[g4] = *(const ushort8v*)(xb + (size_t)s1[g4] * 128 + l16 * 8);
#pragma unroll
            for (int g4 = 0; g4 < 4; g4++)
#pragma unroll
                for (int k = 0; k < 8; k++) ac[g4][k] += b2f(v0[g4][k]);
#pragma unroll
            for (int g4 = 0; g4 < 4; g4++)
#pragma unroll
                for (int k = 0; k < 8; k++) ac[g4][k] += b2f(v1[g4][k]);
        }
#pragma unroll
        for (int g4 = 0; g4 < 4; g4++) {
            for (int j = 16; j < degv[g4]; j++) {
                int s = aj[startv[g4] + j];
                ushort8v v = *(const ushort8v*)(xb + (size_t)s * 128 + l16 * 8);
#pragma unroll
                for (int k = 0; k < 8; k++) ac[g4][k] += b2f(v[k]);
            }
        }
#pragma unroll
        for (int g4 = 0; g4 < 4; g4++) {
            int nl = wave * 16 + g4 * 4 + quad;
            float inv = 1.0f / fmaxf((float)degv[g4], 1.0f);
            ushort8v o;
#pragma unroll
            for (int k = 0; k < 8; k++) o[k] = f2b(ac[g4][k] * inv);
            *(ushort8v*)&s_a[nl * 128 + SW(nl, l16)] = o;
        }
        __syncthreads();

        f32x4 acc[4][2];
#pragma unroll
        for (int g = 0; g < 4; g++) { acc[g][0] = (f32x4){0.f,0.f,0.f,0.f}; acc[g][1] = (f32x4){0.f,0.f,0.f,0.f}; }

        const unsigned short* W = Wfrag + r * 32768 + wave * 8192;
#pragma unroll
        for (int s = 0; s < 8; s++) {
            short8 bf0 = *(const short8*)(W + s * 1024 + lane * 8);
            short8 bf1 = *(const short8*)(W + s * 1024 + 512 + lane * 8);
            const unsigned short* src = (s < 4) ? s_a : s_x;
            int c16 = (s & 3) * 4 + quad;
#pragma unroll
            for (int g = 0; g < 4; g++) {
                int row = g * 16 + l16;
                short8 af = *(const short8*)&src[row * 128 + SW(row, c16)];
                acc[g][0] = __builtin_amdgcn_mfma_f32_16x16x32_bf16(af, bf0, acc[g][0], 0, 0, 0);
                acc[g][1] = __builtin_amdgcn_mfma_f32_16x16x32_bf16(af, bf1, acc[g][1], 0, 0, 0);
            }
        }

        float b0 = bl[r * 128 + wave * 32 + l16];
        float b1 = bl[r * 128 + wave * 32 + 16 + l16];
#pragma unroll
        for (int g = 0; g < 4; g++)
#pragma unroll
            for (int t = 0; t < 2; t++) {
                float bb = t ? b1 : b0;
#pragma unroll
                for (int q = 0; q < 4; q++)
                    hsum[g][t][q] += fmaxf(acc[g][t][q] + bb, 0.f) * (1.0f / 3.0f);
            }
        __syncthreads();
    }

    // direct-scatter epilogue (r11 known-good; L2 write-combines these)
#pragma unroll
    for (int g = 0; g < 4; g++)
#pragma unroll
        for (int t = 0; t < 2; t++) {
            int col = wave * 32 + t * 16 + l16;
#pragma unroll
            for (int q = 0; q < 4; q++) {
                int row = rowbase + g * 16 + quad * 4 + q;
                if (row < N_NODES)
                    hb[(size_t)row * 128 + col] = f2b(hsum[g][t][q]);
            }
        }
}

// ---------------------------------------------------------------------------
// FUSED layer-2 (gather-first): agg2 = mean-gather(h) into swizzled LDS,
// then out = [agg2|h](K=256) @ [Wl_f;Wr_f] + bl_f. 32KB LDS -> 5 blocks/CU.
__global__ __launch_bounds__(256, 4) void fused2_kernel(
    const unsigned short* __restrict__ hb, const int* __restrict__ adj,
    const int* __restrict__ rowstart, const int* __restrict__ cnt,
    const unsigned short* __restrict__ Wfrag2, const float* __restrict__ bl_f,
    float* __restrict__ out) {
    __shared__ unsigned short s_h[64 * 128];
    __shared__ unsigned short s_a[64 * 128];
    int tid = threadIdx.x, wave = tid >> 6, lane = tid & 63;
    int quad = lane >> 4, l16 = lane & 15;
    int rowbase = blockIdx.x * 64;

#pragma unroll
    for (int it = 0; it < 4; it++) {
        int idx = tid + it * 256;
        int row = idx >> 4, c = idx & 15;
        int grow = rowbase + row;
        short8 hv = {0, 0, 0, 0, 0, 0, 0, 0};
        if (grow < N_NODES) hv = *(const short8*)(hb + (size_t)grow * 128 + c * 8);
        *(short8*)&s_h[row * 128 + SW(row, c)] = hv;
    }

    int startv[4], degv[4], jcapv[4], idxv[4];
#pragma unroll
    for (int g4 = 0; g4 < 4; g4++) {
        int node = rowbase + wave * 16 + g4 * 4 + quad;
        bool valid = node < N_NODES;
        startv[g4] = valid ? rowstart[node] : 0;
        degv[g4]   = valid ? cnt[node] : 0;
    }
#pragma unroll
    for (int g4 = 0; g4 < 4; g4++) {
        jcapv[g4] = min(degv[g4], 16);
        idxv[g4] = (l16 < jcapv[g4]) ? adj[startv[g4] + l16] : ZROW;
    }
    int m = max(max(jcapv[0], jcapv[1]), max(jcapv[2], jcapv[3]));
    m = max(m, __shfl_xor(m, 16));
    m = max(m, __shfl_xor(m, 32));

    float ac[4][8];
#pragma unroll
    for (int g4 = 0; g4 < 4; g4++)
#pragma unroll
        for (int k = 0; k < 8; k++) ac[g4][k] = 0.f;

    int sb = quad * 16;
    for (int j = 0; j < m; j += 2) {
        int s0[4], s1[4];
#pragma unroll
        for (int g4 = 0; g4 < 4; g4++) {
            s0[g4] = __shfl(idxv[g4], sb + j);
            s1[g4] = __shfl(idxv[g4], sb + min(j + 1, 15));
        }
        ushort8v v0[4], v1[4];
#pragma unroll
        for (int g4 = 0; g4 < 4; g4++)
            v0[g4] = *(const ushort8v*)(hb + (size_t)s0[g4] * 128 + l16 * 8);
#pragma unroll
        for (int g4 = 0; g4 < 4; g4++)
            v1[g4] = *(const ushort8v*)(hb + (size_t)s1[g4] * 128 + l16 * 8);
#pragma unroll
        for (int g4 = 0; g4 < 4; g4++)
#pragma unroll
            for (int k = 0; k < 8; k++) ac[g4][k] += b2f(v0[g4][k]);
#pragma unroll
        for (int g4 = 0; g4 < 4; g4++)
#pragma unroll
            for (int k = 0; k < 8; k++) ac[g4][k] += b2f(v1[g4][k]);
    }
#pragma unroll
    for (int g4 = 0; g4 < 4; g4++) {
        for (int j = 16; j < degv[g4]; j++) {
            int s = adj[startv[g4] + j];
            ushort8v v = *(const ushort8v*)(hb + (size_t)s * 128 + l16 * 8);
#pragma unroll
            for (int k = 0; k < 8; k++) ac[g4][k] += b2f(v[k]);
        }
    }
#pragma unroll
    for (int g4 = 0; g4 < 4; g4++) {
        int nl = wave * 16 + g4 * 4 + quad;
        float inv = 1.0f / fmaxf((float)degv[g4], 1.0f);
        ushort8v o;
#pragma unroll
        for (int k = 0; k < 8; k++) o[k] = f2b(ac[g4][k] * inv);
        *(ushort8v*)&s_a[nl * 128 + SW(nl, l16)] = o;
    }
    __syncthreads();

    f32x4 acc[4];
#pragma unroll
    for (int g = 0; g < 4; g++) acc[g] = (f32x4){0.f, 0.f, 0.f, 0.f};

    const unsigned short* W = Wfrag2 + wave * 4096;
#pragma unroll
    for (int s = 0; s < 8; s++) {
        short8 bf0 = *(const short8*)(W + s * 512 + lane * 8);
        const unsigned short* src = (s < 4) ? s_a : s_h;
        int c16 = (s & 3) * 4 + quad;
#pragma unroll
        for (int g = 0; g < 4; g++) {
            int row = g * 16 + l16;
            short8 af = *(const short8*)&src[row * 128 + SW(row, c16)];
            acc[g] = __builtin_amdgcn_mfma_f32_16x16x32_bf16(af, bf0, acc[g], 0, 0, 0);
        }
    }

    float bb = bl_f[wave * 16 + l16];
    int col = wave * 16 + l16;
#pragma unroll
    for (int g = 0; g < 4; g++)
#pragma unroll
        for (int q = 0; q < 4; q++) {
            int row = rowbase + g * 16 + quad * 4 + q;
            if (row < N_NODES)
                out[(size_t)row * 64 + col] = acc[g][q] + bb;
        }
}

// ---------------------------------------------------------------------------
extern "C" void kernel_launch(void* const* d_in, const int* in_sizes, int n_in,
                              void* d_out, int out_size, void* d_ws, size_t ws_size,
                              hipStream_t stream) {
    const float* x    = (const float*)d_in[0];
    const float* Wl   = (const float*)d_in[1];
    const float* bl   = (const float*)d_in[2];
    const float* Wr   = (const float*)d_in[3];
    const float* Wl_f = (const float*)d_in[4];
    const float* bl_f = (const float*)d_in[5];
    const float* Wr_f = (const float*)d_in[6];
    const int* ei0 = (const int*)d_in[7];
    const int* ei1 = (const int*)d_in[8];
    const int* ei2 = (const int*)d_in[9];
    float* out = (float*)d_out;

    // workspace layout (offsets), total ~94 MB used
    char* ws = (char*)d_ws;
    int* cnt               = (int*)(ws);                                   // 1.2 MB
    int* bincur            = (int*)(ws + 0x128000);                        // 1.5 KB
    int* rowstart          = (int*)(ws + ((size_t)4  << 20));              // 1.2 MB
    unsigned short* Wfrag  = (unsigned short*)(ws + ((size_t)7  << 20));   // 192 KB
    unsigned short* Wfrag2 = (unsigned short*)(ws + ((size_t)15 << 19));   // 7.5MB, 32 KB
    int* adj               = (int*)(ws + ((size_t)8  << 20));              // 7.2 MB
    unsigned short* xb     = (unsigned short*)(ws + ((size_t)16 << 20));   // 25.6 MB (+ zero row)
    unsigned short* hb     = (unsigned short*)(ws + ((size_t)68 << 20));   // 25.6 MB (+ zero row)
    unsigned* bins         = (unsigned*)(ws + ((size_t)42 << 20));         // 9.4 MB

    hipMemsetAsync(bincur, 0, 3 * SUBP * sizeof(int), stream);
    hipMemsetAsync(xb + (size_t)ZROW * 128, 0, 128 * sizeof(unsigned short), stream);   // zero row
    hipMemsetAsync(hb + (size_t)ZROW * 128, 0, 128 * sizeof(unsigned short), stream);   // zero row

    binprep_kernel<<<BINBLK + 6250 + 448, 256, 0, stream>>>(
        ei0, ei1, ei2, bins, bincur, x, xb, Wl, Wr, Wl_f, Wr_f, Wfrag, Wfrag2);
    csr_kernel<<<dim3(SUBP, 3), 256, 0, stream>>>(bins, bincur, cnt, rowstart, adj);

    const int TILE_BLOCKS = (N_NODES + 63) / 64;     // 1563
    fused1_kernel<<<TILE_BLOCKS, 256, 0, stream>>>(xb, adj, rowstart, cnt, Wfrag, bl, hb);
    fused2_kernel<<<TILE_BLOCKS, 256, 0, stream>>>(hb, adj, rowstart, cnt, Wfrag2, bl_f, out);
}

// Round 15
// 263.994 us; speedup vs baseline: 1.1092x; 1.0011x over previous
//
#include <hip/hip_runtime.h>

#define N_NODES 100000
#define N_EDGES 600000
#define ZROW N_NODES         // sentinel zero-row index (xb/hb/hWlb have N_NODES+1 rows)
#define SUBP 128             // dst sub-partitions
#define SUB_SZ 782           // nodes per sub-partition (128*782 = 100096 >= 100000)
#define ECHUNK 2048          // edges per bin block
#define ACH 293              // ceil(600000/2048)
#define BINBLK (3 * ACH)     // 879 bin blocks in merged front-end kernel
#define BCAP 6144            // per (rel,subpart) bin capacity (mean 4687, +21 sigma)
// LDS tiles: stride 128 ushorts (256B/row), XOR-swizzled 16B units.
#define SW(row, c16) ((((c16) ^ ((row) & 7)) << 3))

typedef __attribute__((ext_vector_type(8))) short short8;
typedef __attribute__((ext_vector_type(4))) float f32x4;
typedef __attribute__((ext_vector_type(4))) unsigned short ushort4v;
typedef __attribute__((ext_vector_type(8))) unsigned short ushort8v;

__device__ __forceinline__ unsigned short f2b(float f) {   // fp32 -> bf16 RNE
    unsigned u = __builtin_bit_cast(unsigned, f);
    return (unsigned short)((u + 0x7fffu + ((u >> 16) & 1u)) >> 16);
}
__device__ __forceinline__ float b2f(unsigned short b) {
    return __builtin_bit_cast(float, (unsigned)b << 16);
}

// ---------------------------------------------------------------------------
// Merged front-end: blocks [0,879) = 128-way edge binning; [879,879+6250) =
// x->bf16 cast; next 448 = weight pre-swizzle; last block = zero-row writer.
__global__ __launch_bounds__(256) void binprep_kernel(
    const int* __restrict__ e0, const int* __restrict__ e1, const int* __restrict__ e2,
    unsigned* __restrict__ bins, int* __restrict__ bincur,
    const float* __restrict__ x, unsigned short* __restrict__ xb,
    const float* __restrict__ Wl, const float* __restrict__ Wr,
    const float* __restrict__ Wl_f, const float* __restrict__ Wr_f,
    unsigned short* __restrict__ Wfrag, unsigned short* __restrict__ Wfrag2,
    unsigned short* __restrict__ hb, unsigned short* __restrict__ hWlb) {
    int bx = blockIdx.x;
    int tid = threadIdx.x;
    if (bx < BINBLK) {
        // ---- bin part: counting sort of edges by dst sub-partition ----
        int r = bx / ACH, chunk = bx % ACH;
        const int* ei = (r == 0) ? e0 : (r == 1 ? e1 : e2);
        int base = chunk * ECHUNK;
        int nhere = min(ECHUNK, N_EDGES - base);
        __shared__ int lhist[SUBP], lstart[SUBP], lcur[SUBP], gbase[SUBP];
        __shared__ unsigned led[ECHUNK];
        __shared__ unsigned char lbkt[ECHUNK];
        for (int i = tid; i < SUBP; i += 256) { lhist[i] = 0; lcur[i] = 0; }
        __syncthreads();
        unsigned pk[8]; int bn[8];
#pragma unroll
        for (int k = 0; k < 8; k++) {
            int i = tid + k * 256;
            bn[k] = -1;
            if (i < nhere) {
                int e = base + i;
                int s = ei[e], d = ei[N_EDGES + e];
                int b = d / SUB_SZ;
                int ld = d - b * SUB_SZ;
                pk[k] = (unsigned)s | ((unsigned)ld << 17);
                bn[k] = b;
                atomicAdd(&lhist[b], 1);
            }
        }
        __syncthreads();
        if (tid == 0) {
            int run = 0;
            for (int b = 0; b < SUBP; b++) { lstart[b] = run; run += lhist[b]; }
        }
        __syncthreads();
#pragma unroll
        for (int k = 0; k < 8; k++) {
            if (bn[k] >= 0) {
                int slot = atomicAdd(&lcur[bn[k]], 1);
                int p = lstart[bn[k]] + slot;
                led[p] = pk[k];
                lbkt[p] = (unsigned char)bn[k];
            }
        }
        if (tid < SUBP) gbase[tid] = atomicAdd(&bincur[r * SUBP + tid], lhist[tid]);
        __syncthreads();
        for (int i = tid; i < nhere; i += 256) {
            int b = lbkt[i];
            int dstidx = gbase[b] + (i - lstart[b]);
            if (dstidx < BCAP)   // safety clamp: drop (never fault) on overflow
                bins[(size_t)(r * SUBP + b) * BCAP + dstidx] = led[i];
        }
        return;
    }
    int pbx = bx - BINBLK;
    if (pbx < 6250) {
        // ---- xcast part ----
        int idx = pbx * 256 + tid;
        const float4* p = (const float4*)x + (size_t)idx * 2;
        float4 a = p[0], b = p[1];
        ushort8v o;
        o[0] = f2b(a.x); o[1] = f2b(a.y); o[2] = f2b(a.z); o[3] = f2b(a.w);
        o[4] = f2b(b.x); o[5] = f2b(b.y); o[6] = f2b(b.z); o[7] = f2b(b.w);
        *(ushort8v*)(xb + (size_t)idx * 8) = o;
        return;
    }
    if (pbx == 6250 + 448) {
        // ---- zero-row writer (sentinel rows; untouched by other writers) ----
        if (tid < 128) {
            xb[(size_t)ZROW * 128 + tid] = 0;
            hb[(size_t)ZROW * 128 + tid] = 0;
        } else if (tid < 192) {
            hWlb[(size_t)ZROW * 64 + (tid - 128)] = 0;
        }
        return;
    }
    // ---- wprep part ----
    int idx = (pbx - 6250) * 256 + tid;            // [0, 114688)
    int j = idx & 7, lane = (idx >> 3) & 63;
    int quad = lane >> 4, l16 = lane & 15;
    if (idx < 98304) {
        int t = (idx >> 9) & 1, s = (idx >> 10) & 7, w = (idx >> 13) & 3, r = idx >> 15;
        int k = s * 32 + quad * 8 + j;
        int n = w * 32 + t * 16 + l16;
        float v = (k < 128) ? Wl[((size_t)r * 128 + k) * 128 + n]
                            : Wr[((size_t)r * 128 + (k - 128)) * 128 + n];
        Wfrag[idx] = f2b(v);
    } else {
        int i2 = idx - 98304;
        if (i2 < 16384) {
            int s = (i2 >> 9) & 7, w = i2 >> 12;
            int k = s * 32 + quad * 8 + j;
            int n = w * 16 + l16;
            float v = (k < 128) ? Wl_f[(size_t)k * 64 + n] : Wr_f[(size_t)(k - 128) * 64 + n];
            Wfrag2[i2] = f2b(v);
        }
    }
}

// ---------------------------------------------------------------------------
// Consolidated CSR build: one block per (rel,subpart). Inline pbase prefix
// (wave 3) + LDS histogram -> in-LDS scan -> cnt/rowstart -> LDS-cursor fill
// -> coalesced adj streaming.
__global__ __launch_bounds__(256) void csr_kernel(const unsigned* __restrict__ bins,
                                                  const int* __restrict__ bincur,
                                                  int* __restrict__ cnt,
                                                  int* __restrict__ rowstart,
                                                  int* __restrict__ adj) {
    int p = blockIdx.x, r = blockIdx.y;
    int n0 = p * SUB_SZ;
    int nodes = min(SUB_SZ, N_NODES - n0);
    __shared__ int hist[SUB_SZ];
    __shared__ int sstage[BCAP];
    __shared__ int wsums[4];
    __shared__ int s_pb;
    int tid = threadIdx.x, lane = tid & 63, wid = tid >> 6;
    for (int i = tid; i < SUB_SZ; i += 256) hist[i] = 0;
    if (wid == 3) {   // inline prefix over this relation's partition totals
        int v0 = (lane < p) ? bincur[r * SUBP + lane] : 0;
        int v1 = (lane + 64 < p) ? bincur[r * SUBP + 64 + lane] : 0;
        int s = v0 + v1;
#pragma unroll
        for (int off = 1; off < 64; off <<= 1) s += __shfl_xor(s, off);
        if (lane == 0) s_pb = s;
    }
    __syncthreads();
    int len = min(bincur[r * SUBP + p], BCAP);
    const unsigned* b = bins + (size_t)(r * SUBP + p) * BCAP;
    for (int i = tid; i < len; i += 256) atomicAdd(&hist[b[i] >> 17], 1);
    __syncthreads();
    int base4 = tid * 4;
    int v[4]; int tsum = 0;
#pragma unroll
    for (int k = 0; k < 4; k++) {
        int i = base4 + k;
        v[k] = (i < SUB_SZ) ? hist[i] : 0;
        tsum += v[k];
    }
    for (int i = tid; i < nodes; i += 256) cnt[r * N_NODES + n0 + i] = hist[i];
    int incl = tsum;
#pragma unroll
    for (int off = 1; off < 64; off <<= 1) {
        int t = __shfl_up(incl, off);
        if (lane >= off) incl += t;
    }
    if (lane == 63) wsums[wid] = incl;
    __syncthreads();
    if (tid == 0) { int run = 0; for (int w = 0; w < 4; w++) { int t = wsums[w]; wsums[w] = run; run += t; } }
    __syncthreads();
    int excl = incl - tsum + wsums[wid];
    int pb = s_pb;
    int run = excl;
#pragma unroll
    for (int k = 0; k < 4; k++) {
        int i = base4 + k;
        if (i < SUB_SZ) {
            if (i < nodes) rowstart[r * N_NODES + n0 + i] = pb + run;
            hist[i] = run;              // local cursor seed
        }
        run += v[k];
    }
    __syncthreads();
    for (int i = tid; i < len; i += 256) {
        unsigned vv = b[i];
        int pos = atomicAdd(&hist[vv >> 17], 1);
        if (pos < BCAP) sstage[pos] = (int)(vv & 0x1FFFFu);
    }
    __syncthreads();
    int* a = adj + (size_t)r * N_EDGES + pb;
    for (int i = tid; i < len; i += 256) a[i] = sstage[i];
}

// ---------------------------------------------------------------------------
// FUSED layer-1: branch-free pipelined gather (ZROW sentinel), swizzled 32KB
// LDS, direct-scatter hb epilogue, PLUS hWl = h @ Wl_f projection (K=128 MFMA
// via s_a round-trip) so fused2 gathers 128B rows instead of 256B.
__global__ __launch_bounds__(256, 4) void fused1_kernel(
    const unsigned short* __restrict__ xb, const int* __restrict__ adj,
    const int* __restrict__ rowstart, const int* __restrict__ cnt,
    const unsigned short* __restrict__ Wfrag, const unsigned short* __restrict__ Wfrag2,
    const float* __restrict__ bl, unsigned short* __restrict__ hb,
    unsigned short* __restrict__ hWlb) {
    __shared__ unsigned short s_x[64 * 128];
    __shared__ unsigned short s_a[64 * 128];
    int tid = threadIdx.x, wave = tid >> 6, lane = tid & 63;
    int quad = lane >> 4, l16 = lane & 15;
    int rowbase = blockIdx.x * 64;

#pragma unroll
    for (int it = 0; it < 4; it++) {
        int idx = tid + it * 256;
        int row = idx >> 4, c = idx & 15;
        int grow = rowbase + row;
        short8 xv = {0, 0, 0, 0, 0, 0, 0, 0};
        if (grow < N_NODES) xv = *(const short8*)(xb + (size_t)grow * 128 + c * 8);
        *(short8*)&s_x[row * 128 + SW(row, c)] = xv;
    }

    f32x4 hsum[4][2];
#pragma unroll
    for (int g = 0; g < 4; g++) { hsum[g][0] = (f32x4){0.f,0.f,0.f,0.f}; hsum[g][1] = (f32x4){0.f,0.f,0.f,0.f}; }

    for (int r = 0; r < 3; r++) {
        const int* rs = rowstart + r * N_NODES;
        const int* ct = cnt + r * N_NODES;
        const int* aj = adj + (size_t)r * N_EDGES;

        int startv[4], degv[4], jcapv[4], idxv[4];
#pragma unroll
        for (int g4 = 0; g4 < 4; g4++) {
            int node = rowbase + wave * 16 + g4 * 4 + quad;
            bool valid = node < N_NODES;
            startv[g4] = valid ? rs[node] : 0;
            degv[g4]   = valid ? ct[node] : 0;
        }
#pragma unroll
        for (int g4 = 0; g4 < 4; g4++) {
            jcapv[g4] = min(degv[g4], 16);
            idxv[g4] = (l16 < jcapv[g4]) ? aj[startv[g4] + l16] : ZROW;
        }
        int m = max(max(jcapv[0], jcapv[1]), max(jcapv[2], jcapv[3]));
        m = max(m, __shfl_xor(m, 16));
        m = max(m, __shfl_xor(m, 32));

        float ac[4][8];
#pragma unroll
        for (int g4 = 0; g4 < 4; g4++)
#pragma unroll
            for (int k = 0; k < 8; k++) ac[g4][k] = 0.f;

        int sb = quad * 16;
        for (int j = 0; j < m; j += 2) {
            int s0[4], s1[4];
#pragma unroll
            for (int g4 = 0; g4 < 4; g4++) {
                s0[g4] = __shfl(idxv[g4], sb + j);
                s1[g4] = __shfl(idxv[g4], sb + min(j + 1, 15));
            }
            ushort8v v0[4], v1[4];
#pragma unroll
            for (int g4 = 0; g4 < 4; g4++)
                v0[g4] = *(const ushort8v*)(xb + (size_t)s0[g4] * 128 + l16 * 8);
#pragma unroll
            for (int g4 = 0; g4 < 4; g4++)
                v1[g4] = *(const ushort8v*)(xb + (size_t)s1[g4] * 128 + l16 * 8);
#pragma unroll
            for (int g4 = 0; g4 < 4; g4++)
#pragma unroll
                for (int k = 0; k < 8; k++) ac[g4][k] += b2f(v0[g4][k]);
#pragma unroll
            for (int g4 = 0; g4 < 4; g4++)
#pragma unroll
                for (int k = 0; k < 8; k++) ac[g4][k] += b2f(v1[g4][k]);
        }
#pragma unroll
        for (int g4 = 0; g4 < 4; g4++) {
            for (int j = 16; j < degv[g4]; j++) {
                int s = aj[startv[g4] + j];
                ushort8v v = *(const ushort8v*)(xb + (size_t)s * 128 + l16 * 8);
#pragma unroll
                for (int k = 0; k < 8; k++) ac[g4][k] += b2f(v[k]);
            }
        }
#pragma unroll
        for (int g4 = 0; g4 < 4; g4++) {
            int nl = wave * 16 + g4 * 4 + quad;
            float inv = 1.0f / fmaxf((float)degv[g4], 1.0f);
            ushort8v o;
#pragma unroll
            for (int k = 0; k < 8; k++) o[k] = f2b(ac[g4][k] * inv);
            *(ushort8v*)&s_a[nl * 128 + SW(nl, l16)] = o;
        }
        __syncthreads();

        f32x4 acc[4][2];
#pragma unroll
        for (int g = 0; g < 4; g++) { acc[g][0] = (f32x4){0.f,0.f,0.f,0.f}; acc[g][1] = (f32x4){0.f,0.f,0.f,0.f}; }

        const unsigned short* W = Wfrag + r * 32768 + wave * 8192;
#pragma unroll
        for (int s = 0; s < 8; s++) {
            short8 bf0 = *(const short8*)(W + s * 1024 + lane * 8);
            short8 bf1 = *(const short8*)(W + s * 1024 + 512 + lane * 8);
            const unsigned short* src = (s < 4) ? s_a : s_x;
            int c16 = (s & 3) * 4 + quad;
#pragma unroll
            for (int g = 0; g < 4; g++) {
                int row = g * 16 + l16;
                short8 af = *(const short8*)&src[row * 128 + SW(row, c16)];
                acc[g][0] = __builtin_amdgcn_mfma_f32_16x16x32_bf16(af, bf0, acc[g][0], 0, 0, 0);
                acc[g][1] = __builtin_amdgcn_mfma_f32_16x16x32_bf16(af, bf1, acc[g][1], 0, 0, 0);
            }
        }

        float b0 = bl[r * 128 + wave * 32 + l16];
        float b1 = bl[r * 128 + wave * 32 + 16 + l16];
#pragma unroll
        for (int g = 0; g < 4; g++)
#pragma unroll
            for (int t = 0; t < 2; t++) {
                float bb = t ? b1 : b0;
#pragma unroll
                for (int q = 0; q < 4; q++)
                    hsum[g][t][q] += fmaxf(acc[g][t][q] + bb, 0.f) * (1.0f / 3.0f);
            }
        __syncthreads();
    }

    // epilogue A: direct-scatter hb (r11 known-good)
#pragma unroll
    for (int g = 0; g < 4; g++)
#pragma unroll
        for (int t = 0; t < 2; t++) {
            int col = wave * 32 + t * 16 + l16;
#pragma unroll
            for (int q = 0; q < 4; q++) {
                int row = rowbase + g * 16 + quad * 4 + q;
                if (row < N_NODES)
                    hb[(size_t)row * 128 + col] = f2b(hsum[g][t][q]);
            }
        }

    // epilogue B: hsum -> s_a (bf16), then hWl = h @ Wl_f (K=128) -> hWlb
#pragma unroll
    for (int g = 0; g < 4; g++)
#pragma unroll
        for (int t = 0; t < 2; t++) {
            int col = wave * 32 + t * 16 + l16;
            int cu = col >> 3, ci = col & 7;
#pragma unroll
            for (int q = 0; q < 4; q++) {
                int row = g * 16 + quad * 4 + q;
                s_a[row * 128 + SW(row, cu) + ci] = f2b(hsum[g][t][q]);
            }
        }
    __syncthreads();

    f32x4 acc2[4];
#pragma unroll
    for (int g = 0; g < 4; g++) acc2[g] = (f32x4){0.f, 0.f, 0.f, 0.f};
    const unsigned short* W2 = Wfrag2 + wave * 4096;
#pragma unroll
    for (int s = 0; s < 4; s++) {        // k < 128 half = Wl_f
        short8 bf0 = *(const short8*)(W2 + s * 512 + lane * 8);
        int c16 = s * 4 + quad;
#pragma unroll
        for (int g = 0; g < 4; g++) {
            int row = g * 16 + l16;
            short8 af = *(const short8*)&s_a[row * 128 + SW(row, c16)];
            acc2[g] = __builtin_amdgcn_mfma_f32_16x16x32_bf16(af, bf0, acc2[g], 0, 0, 0);
        }
    }
    int col2 = wave * 16 + l16;
#pragma unroll
    for (int g = 0; g < 4; g++)
#pragma unroll
        for (int q = 0; q < 4; q++) {
            int row = rowbase + g * 16 + quad * 4 + q;
            if (row < N_NODES)
                hWlb[(size_t)row * 64 + col2] = f2b(acc2[g][q]);
        }
}

// ---------------------------------------------------------------------------
// FUSED layer-2: out = mean-gather(hWlb rows, 128B) + h @ Wr_f + bl_f.
// Gather is lane-private (16 lanes x ushort4 per row); self-term MFMA from
// staged s_h; combine via s_h reused as a float buffer. LDS = 16KB.
__global__ __launch_bounds__(256, 4) void fused2_kernel(
    const unsigned short* __restrict__ hb, const unsigned short* __restrict__ hWlb,
    const int* __restrict__ adj, const int* __restrict__ rowstart,
    const int* __restrict__ cnt, const unsigned short* __restrict__ Wfrag2,
    const float* __restrict__ bl_f, float* __restrict__ out) {
    __shared__ unsigned short s_h[64 * 128];
    int tid = threadIdx.x, wave = tid >> 6, lane = tid & 63;
    int quad = lane >> 4, l16 = lane & 15;
    int rowbase = blockIdx.x * 64;

#pragma unroll
    for (int it = 0; it < 4; it++) {
        int idx = tid + it * 256;
        int row = idx >> 4, c = idx & 15;
        int grow = rowbase + row;
        short8 hv = {0, 0, 0, 0, 0, 0, 0, 0};
        if (grow < N_NODES) hv = *(const short8*)(hb + (size_t)grow * 128 + c * 8);
        *(short8*)&s_h[row * 128 + SW(row, c)] = hv;
    }
    __syncthreads();

    // gather mean(hWlb) for 16 nodes/wave; lane l16 owns channels l16*4..+4
    int startv[4], degv[4], jcapv[4], idxv[4];
#pragma unroll
    for (int g4 = 0; g4 < 4; g4++) {
        int node = rowbase + wave * 16 + g4 * 4 + quad;
        bool valid = node < N_NODES;
        startv[g4] = valid ? rowstart[node] : 0;
        degv[g4]   = valid ? cnt[node] : 0;
    }
#pragma unroll
    for (int g4 = 0; g4 < 4; g4++) {
        jcapv[g4] = min(degv[g4], 16);
        idxv[g4] = (l16 < jcapv[g4]) ? adj[startv[g4] + l16] : ZROW;
    }
    int m = max(max(jcapv[0], jcapv[1]), max(jcapv[2], jcapv[3]));
    m = max(m, __shfl_xor(m, 16));
    m = max(m, __shfl_xor(m, 32));

    float ag[4][4];
#pragma unroll
    for (int g4 = 0; g4 < 4; g4++)
#pragma unroll
        for (int k = 0; k < 4; k++) ag[g4][k] = 0.f;

    int sb = quad * 16;
    for (int j = 0; j < m; j += 2) {
        int s0[4], s1[4];
#pragma unroll
        for (int g4 = 0; g4 < 4; g4++) {
            s0[g4] = __shfl(idxv[g4], sb + j);
            s1[g4] = __shfl(idxv[g4], sb + min(j + 1, 15));
        }
        ushort4v v0[4], v1[4];
#pragma unroll
        for (int g4 = 0; g4 < 4; g4++)
            v0[g4] = *(const ushort4v*)(hWlb + (size_t)s0[g4] * 64 + l16 * 4);
#pragma unroll
        for (int g4 = 0; g4 < 4; g4++)
            v1[g4] = *(const ushort4v*)(hWlb + (size_t)s1[g4] * 64 + l16 * 4);
#pragma unroll
        for (int g4 = 0; g4 < 4; g4++) {
            ag[g4][0] += b2f(v0[g4].x) + b2f(v1[g4].x);
            ag[g4][1] += b2f(v0[g4].y) + b2f(v1[g4].y);
            ag[g4][2] += b2f(v0[g4].z) + b2f(v1[g4].z);
            ag[g4][3] += b2f(v0[g4].w) + b2f(v1[g4].w);
        }
    }
#pragma unroll
    for (int g4 = 0; g4 < 4; g4++) {
        for (int j = 16; j < degv[g4]; j++) {
            int s = adj[startv[g4] + j];
            ushort4v v = *(const ushort4v*)(hWlb + (size_t)s * 64 + l16 * 4);
            ag[g4][0] += b2f(v.x); ag[g4][1] += b2f(v.y);
            ag[g4][2] += b2f(v.z); ag[g4][3] += b2f(v.w);
        }
    }

    // self-term: h @ Wr_f (K=128, k>=128 half of Wfrag2)
    f32x4 acc[4];
#pragma unroll
    for (int g = 0; g < 4; g++) acc[g] = (f32x4){0.f, 0.f, 0.f, 0.f};
    const unsigned short* W = Wfrag2 + wave * 4096;
#pragma unroll
    for (int s = 4; s < 8; s++) {
        short8 bf0 = *(const short8*)(W + s * 512 + lane * 8);
        int c16 = (s & 3) * 4 + quad;
#pragma unroll
        for (int g = 0; g < 4; g++) {
            int row = g * 16 + l16;
            short8 af = *(const short8*)&s_h[row * 128 + SW(row, c16)];
            acc[g] = __builtin_amdgcn_mfma_f32_16x16x32_bf16(af, bf0, acc[g], 0, 0, 0);
        }
    }
    __syncthreads();   // s_h reads done; reuse as float buffer

    float* fl = (float*)s_h;            // [64][64] floats = 16KB
#pragma unroll
    for (int g4 = 0; g4 < 4; g4++) {
        int nl = wave * 16 + g4 * 4 + quad;
        float inv = 1.0f / fmaxf((float)degv[g4], 1.0f);
        f32x4 o;
#pragma unroll
        for (int k = 0; k < 4; k++) o[k] = ag[g4][k] * inv;
        *(f32x4*)&fl[nl * 64 + l16 * 4] = o;
    }
    __syncthreads();

    float bb = bl_f[wave * 16 + l16];
    int col = wave * 16 + l16;
#pragma unroll
    for (int g = 0; g < 4; g++)
#pragma unroll
        for (int q = 0; q < 4; q++) {
            int rl = g * 16 + quad * 4 + q;
            int row = rowbase + rl;
            if (row < N_NODES)
                out[(size_t)row * 64 + col] = acc[g][q] + fl[rl * 64 + col] + bb;
        }
}

// ---------------------------------------------------------------------------
extern "C" void kernel_launch(void* const* d_in, const int* in_sizes, int n_in,
                              void* d_out, int out_size, void* d_ws, size_t ws_size,
                              hipStream_t stream) {
    const float* x    = (const float*)d_in[0];
    const float* Wl   = (const float*)d_in[1];
    const float* bl   = (const float*)d_in[2];
    const float* Wr   = (const float*)d_in[3];
    const float* Wl_f = (const float*)d_in[4];
    const float* bl_f = (const float*)d_in[5];
    const float* Wr_f = (const float*)d_in[6];
    const int* ei0 = (const int*)d_in[7];
    const int* ei1 = (const int*)d_in[8];
    const int* ei2 = (const int*)d_in[9];
    float* out = (float*)d_out;

    // workspace layout (offsets), total ~107 MB used
    char* ws = (char*)d_ws;
    int* cnt               = (int*)(ws);                                   // 1.2 MB
    int* bincur            = (int*)(ws + 0x128000);                        // 1.5 KB
    int* rowstart          = (int*)(ws + ((size_t)4  << 20));              // 1.2 MB
    unsigned short* Wfrag  = (unsigned short*)(ws + ((size_t)7  << 20));   // 192 KB
    unsigned short* Wfrag2 = (unsigned short*)(ws + ((size_t)15 << 19));   // 7.5MB, 32 KB
    int* adj               = (int*)(ws + ((size_t)8  << 20));              // 7.2 MB
    unsigned short* xb     = (unsigned short*)(ws + ((size_t)16 << 20));   // 25.6 MB (+ zero row)
    unsigned short* hb     = (unsigned short*)(ws + ((size_t)68 << 20));   // 25.6 MB (+ zero row)
    unsigned short* hWlb   = (unsigned short*)(ws + ((size_t)94 << 20));   // 12.8 MB (+ zero row)
    unsigned* bins         = (unsigned*)(ws + ((size_t)42 << 20));         // 9.4 MB

    hipMemsetAsync(bincur, 0, 3 * SUBP * sizeof(int), stream);

    binprep_kernel<<<BINBLK + 6250 + 448 + 1, 256, 0, stream>>>(
        ei0, ei1, ei2, bins, bincur, x, xb, Wl, Wr, Wl_f, Wr_f, Wfrag, Wfrag2, hb, hWlb);
    csr_kernel<<<dim3(SUBP, 3), 256, 0, stream>>>(bins, bincur, cnt, rowstart, adj);

    const int TILE_BLOCKS = (N_NODES + 63) / 64;     // 1563
    fused1_kernel<<<TILE_BLOCKS, 256, 0, stream>>>(
        xb, adj, rowstart, cnt, Wfrag, Wfrag2, bl, hb, hWlb);
    fused2_kernel<<<TILE_BLOCKS, 256, 0, stream>>>(
        hb, hWlb, adj, rowstart, cnt, Wfrag2, bl_f, out);
}